// Round 14
// baseline (608.783 us; speedup 1.0000x reference)
//
#include <hip/hip_runtime.h>
#include <hip/hip_bf16.h>
#include <math.h>

#define B_   8
#define L_   1024
#define DM_  256
#define NL_  4
#define ED_  512
#define NS_  16
#define DC_  4
#define RK_  16
#define CD_  64
#define Q_   2

#define SEG_  16    // segments along L
#define SLEN_ 64    // L_/SEG_

typedef __hip_bfloat16 bf16_t;
typedef __attribute__((ext_vector_type(8))) short short8;
typedef __attribute__((ext_vector_type(4))) float floatx4;

__device__ __forceinline__ float geluf(float x) {
    return 0.5f * x * (1.0f + erff(x * 0.70710678118654752f));
}
__device__ __forceinline__ float siluf(float x) {
    return x / (1.0f + __expf(-x));
}
__device__ __forceinline__ float softplusf(float x) {
    return (x > 20.0f) ? x : log1pf(expf(x));
}
__device__ __forceinline__ float b2f(bf16_t v) { return __bfloat162float(v); }
__device__ __forceinline__ float bits2f(short u) {
    return __uint_as_float(((unsigned)(unsigned short)u) << 16);
}
__device__ __forceinline__ short f2bfbits(float v) {
    return __builtin_bit_cast(short, __float2bfloat16(v));
}

// ---------------- one-shot batched weight transpose + bf16 convert
__global__ void k_transpose_all(const float* __restrict__ in_w,
                                const float* __restrict__ xp_w,
                                const float* __restrict__ out_w,
                                bf16_t* __restrict__ in_wT,
                                bf16_t* __restrict__ xp_wT,
                                bf16_t* __restrict__ out_wT) {
    __shared__ float t[32][33];
    int z = blockIdx.z;
    int which = z >> 2, layer = z & 3;
    const float* src; bf16_t* dst; int R, C;
    if (which == 0)      { R = DM_; C = 2 * ED_; src = in_w;  dst = in_wT;  }
    else if (which == 1) { R = ED_; C = 48;      src = xp_w;  dst = xp_wT;  }
    else                 { R = ED_; C = DM_;     src = out_w; dst = out_wT; }
    src += (size_t)layer * R * C;
    dst += (size_t)layer * R * C;
    int c0 = blockIdx.x * 32, r0 = blockIdx.y * 32;
    if (c0 >= C || r0 >= R) return;
    int tx = threadIdx.x & 31, ty = threadIdx.x >> 5;   // 32 x 8
    #pragma unroll
    for (int i = 0; i < 32; i += 8) {
        int r = r0 + ty + i, c = c0 + tx;
        t[ty + i][tx] = (r < R && c < C) ? src[(size_t)r * C + c] : 0.f;
    }
    __syncthreads();
    #pragma unroll
    for (int i = 0; i < 32; i += 8) {
        int c = c0 + ty + i, r = r0 + tx;
        if (c < C && r < R) dst[(size_t)c * R + r] = __float2bfloat16(t[tx][ty + i]);
    }
}

// ---------------- embed
__global__ void k_embed(const int* __restrict__ tokens,
                        const float* __restrict__ tok_embed,
                        const float* __restrict__ pos_embed,
                        float* __restrict__ x) {
    int row = blockIdx.x;
    int d = threadIdx.x;
    int b = row / L_, l = row % L_;
    float v = pos_embed[l * DM_ + d];
    if (l > 0) {
        int tok = tokens[b * L_ + l - 1];
        v += tok_embed[tok * DM_ + d];
    }
    x[row * DM_ + d] = v;
}

// ---------------- conditioning + all-layer adaLN params in one launch
__global__ void k_prep(const float* __restrict__ T,
                       const float* __restrict__ tw1, const float* __restrict__ tb1,
                       const float* __restrict__ tw2, const float* __restrict__ tb2,
                       const float* __restrict__ apw, const float* __restrict__ apb,
                       float* __restrict__ ss) {
    __shared__ float h[CD_], cnd[CD_];
    int b = blockIdx.x, layer = blockIdx.y;
    int j = threadIdx.x;
    if (j < CD_) h[j] = geluf(T[b] * tw1[j] + tb1[j]);
    __syncthreads();
    if (j < CD_) {
        float acc = tb2[j];
        #pragma unroll
        for (int c = 0; c < CD_; c++) acc += h[c] * tw2[c * CD_ + j];
        cnd[j] = acc;
    }
    __syncthreads();
    const float* w = apw + (size_t)layer * CD_ * 2 * DM_;
    float acc = apb[layer * 2 * DM_ + j];
    #pragma unroll
    for (int c = 0; c < CD_; c++) acc += cnd[c] * w[c * 2 * DM_ + j];
    ss[((size_t)layer * B_ + b) * 2 * DM_ + j] = acc;
}

// ---------------- fused LN+adaLN + in-projection MFMA GEMM
// xz[8192][1024] = mod(LN(x)) @ in_wT^T, silu applied to cols >= ED_.
__global__ __launch_bounds__(256) void k_ln_gemm_in(
        const float* __restrict__ x,
        const float* __restrict__ ag, const float* __restrict__ ab,
        const float* __restrict__ ss,
        const bf16_t* __restrict__ Bt,
        bf16_t* __restrict__ xz, int layer) {
    constexpr int BM = 128, BN = 128, K = 256, N = 2 * ED_;
    constexpr int TM = 4, TN = 4;
    __shared__ __align__(16) unsigned short sA[BM * 40];
    __shared__ __align__(16) unsigned short sB[BN * 40];
    __shared__ float s_mr[BM][2];
    __shared__ float s_prm[4 * DM_];   // g | b | (1+sc) | sh

    const int tid = threadIdx.x;
    const int wave = tid >> 6, lane = tid & 63;
    const int lrow = lane & 15, lq = lane >> 4;
    const int row0 = blockIdx.y * BM, col0 = blockIdx.x * BN;
    const int b = row0 / L_;
    const int wm0 = (wave >> 1) * 64, wn0 = (wave & 1) * 64;

    {
        s_prm[tid]       = ag[layer * DM_ + tid];
        s_prm[256 + tid] = ab[layer * DM_ + tid];
        const float* ssl = ss + ((size_t)layer * B_ + b) * 2 * DM_;
        s_prm[512 + tid] = 1.0f + ssl[tid];
        s_prm[768 + tid] = ssl[DM_ + tid];
    }
    {
        int r = tid >> 1, half = tid & 1;
        const float* xr = x + (size_t)(row0 + r) * K + half * 128;
        float s = 0.f, q = 0.f;
        #pragma unroll
        for (int i = 0; i < 32; i++) {
            float4 v = *(const float4*)(xr + i * 4);
            s += (v.x + v.y) + (v.z + v.w);
            q += (v.x * v.x + v.y * v.y) + (v.z * v.z + v.w * v.w);
        }
        s += __shfl_xor(s, 1, 64);
        q += __shfl_xor(q, 1, 64);
        if (!half) {
            float mean = s * (1.0f / K);
            float var = q * (1.0f / K) - mean * mean;
            s_mr[r][0] = mean;
            s_mr[r][1] = rsqrtf(var + 1e-5f);
        }
    }

    floatx4 acc[TM][TN];
    #pragma unroll
    for (int i = 0; i < TM; i++)
        #pragma unroll
        for (int j = 0; j < TN; j++) acc[i][j] = (floatx4)0.0f;

    float4 raf[2][2];
    short8 rb[2];
    const int NKB = K / 32;   // 8
    #pragma unroll
    for (int i = 0; i < 2; i++) {
        int v = tid + i * 256; int m = v >> 2, ko = (v & 3) * 8;
        raf[i][0] = *(const float4*)(x + (size_t)(row0 + m) * K + ko);
        raf[i][1] = *(const float4*)(x + (size_t)(row0 + m) * K + ko + 4);
    }
    #pragma unroll
    for (int i = 0; i < 2; i++) {
        int v = tid + i * 256; int n = v >> 2, ko = (v & 3) * 8;
        rb[i] = *(const short8*)(Bt + (size_t)(col0 + n) * K + ko);
    }

    for (int kb = 0; kb < NKB; kb++) {
        __syncthreads();
        #pragma unroll
        for (int i = 0; i < 2; i++) {
            int v = tid + i * 256; int m = v >> 2, ko = (v & 3) * 8;
            int c0 = kb * 32 + ko;
            float mean = s_mr[m][0], rstd = s_mr[m][1];
            float av[8] = {raf[i][0].x, raf[i][0].y, raf[i][0].z, raf[i][0].w,
                           raf[i][1].x, raf[i][1].y, raf[i][1].z, raf[i][1].w};
            short8 o;
            #pragma unroll
            for (int j = 0; j < 8; j++) {
                int c = c0 + j;
                float ln = (av[j] - mean) * rstd * s_prm[c] + s_prm[256 + c];
                o[j] = f2bfbits(s_prm[512 + c] * ln + s_prm[768 + c]);
            }
            *(short8*)&sA[m * 40 + ko] = o;
        }
        #pragma unroll
        for (int i = 0; i < 2; i++) {
            int v = tid + i * 256; int n = v >> 2, ko = (v & 3) * 8;
            *(short8*)&sB[n * 40 + ko] = rb[i];
        }
        __syncthreads();
        if (kb + 1 < NKB) {
            int k0 = (kb + 1) * 32;
            #pragma unroll
            for (int i = 0; i < 2; i++) {
                int v = tid + i * 256; int m = v >> 2, ko = (v & 3) * 8;
                raf[i][0] = *(const float4*)(x + (size_t)(row0 + m) * K + k0 + ko);
                raf[i][1] = *(const float4*)(x + (size_t)(row0 + m) * K + k0 + ko + 4);
            }
            #pragma unroll
            for (int i = 0; i < 2; i++) {
                int v = tid + i * 256; int n = v >> 2, ko = (v & 3) * 8;
                rb[i] = *(const short8*)(Bt + (size_t)(col0 + n) * K + k0 + ko);
            }
        }
        short8 af[TM], bfr[TN];
        #pragma unroll
        for (int i = 0; i < TM; i++)
            af[i] = *(const short8*)&sA[(wm0 + i * 16 + lrow) * 40 + lq * 8];
        #pragma unroll
        for (int j = 0; j < TN; j++)
            bfr[j] = *(const short8*)&sB[(wn0 + j * 16 + lrow) * 40 + lq * 8];
        #pragma unroll
        for (int i = 0; i < TM; i++)
            #pragma unroll
            for (int j = 0; j < TN; j++)
                acc[i][j] = __builtin_amdgcn_mfma_f32_16x16x32_bf16(af[i], bfr[j], acc[i][j], 0, 0, 0);
    }

    #pragma unroll
    for (int i = 0; i < TM; i++) {
        int gr0 = row0 + wm0 + i * 16 + lq * 4;
        #pragma unroll
        for (int j = 0; j < TN; j++) {
            int gc = col0 + wn0 + j * 16 + lrow;
            #pragma unroll
            for (int r = 0; r < 4; r++) {
                float val = acc[i][j][r];
                if (gc >= ED_) val = siluf(val);
                xz[(size_t)(gr0 + r) * N + gc] = __float2bfloat16(val);
            }
        }
    }
}

// ---------------- MFMA bf16 GEMM (out-projection): C[M,N] += A[M,K] @ Bt[N,K]^T
template<int BM, int BN>
__global__ __launch_bounds__(256) void k_mfma_gemm_acc(
        const bf16_t* __restrict__ A, const bf16_t* __restrict__ Bt,
        float* __restrict__ Cf, int M, int N, int K) {
    constexpr int TM = BM / 32, TN = BN / 32;
    constexpr int VA = BM * 4, VB = BN * 4;
    constexpr int NA = (VA + 255) / 256;
    constexpr int NB = (VB + 255) / 256;
    __shared__ __align__(16) unsigned short sA[BM * 40];
    __shared__ __align__(16) unsigned short sB[BN * 40];

    const int tid = threadIdx.x;
    const int wave = tid >> 6, lane = tid & 63;
    const int lrow = lane & 15, lq = lane >> 4;
    const int row0 = blockIdx.y * BM, col0 = blockIdx.x * BN;
    const int wm0 = (wave >> 1) * (BM / 2);
    const int wn0 = (wave & 1) * (BN / 2);

    floatx4 acc[TM][TN];
    #pragma unroll
    for (int i = 0; i < TM; i++)
        #pragma unroll
        for (int j = 0; j < TN; j++) acc[i][j] = (floatx4)0.0f;

    short8 ra[NA], rb[NB];
    const int NKB = K / 32;

    #pragma unroll
    for (int i = 0; i < NA; i++) {
        int v = tid + i * 256;
        if (v < VA) {
            int m = v >> 2, ko = (v & 3) * 8;
            ra[i] = *(const short8*)(A + (size_t)(row0 + m) * K + ko);
        }
    }
    #pragma unroll
    for (int i = 0; i < NB; i++) {
        int v = tid + i * 256;
        if (v < VB) {
            int n = v >> 2, ko = (v & 3) * 8;
            rb[i] = *(const short8*)(Bt + (size_t)(col0 + n) * K + ko);
        }
    }

    for (int kb = 0; kb < NKB; kb++) {
        __syncthreads();
        #pragma unroll
        for (int i = 0; i < NA; i++) {
            int v = tid + i * 256;
            if (v < VA) {
                int m = v >> 2, ko = (v & 3) * 8;
                *(short8*)&sA[m * 40 + ko] = ra[i];
            }
        }
        #pragma unroll
        for (int i = 0; i < NB; i++) {
            int v = tid + i * 256;
            if (v < VB) {
                int n = v >> 2, ko = (v & 3) * 8;
                *(short8*)&sB[n * 40 + ko] = rb[i];
            }
        }
        __syncthreads();
        if (kb + 1 < NKB) {
            int k0 = (kb + 1) * 32;
            #pragma unroll
            for (int i = 0; i < NA; i++) {
                int v = tid + i * 256;
                if (v < VA) {
                    int m = v >> 2, ko = (v & 3) * 8;
                    ra[i] = *(const short8*)(A + (size_t)(row0 + m) * K + k0 + ko);
                }
            }
            #pragma unroll
            for (int i = 0; i < NB; i++) {
                int v = tid + i * 256;
                if (v < VB) {
                    int n = v >> 2, ko = (v & 3) * 8;
                    rb[i] = *(const short8*)(Bt + (size_t)(col0 + n) * K + k0 + ko);
                }
            }
        }
        short8 af[TM], bfr[TN];
        #pragma unroll
        for (int i = 0; i < TM; i++)
            af[i] = *(const short8*)&sA[(wm0 + i * 16 + lrow) * 40 + lq * 8];
        #pragma unroll
        for (int j = 0; j < TN; j++)
            bfr[j] = *(const short8*)&sB[(wn0 + j * 16 + lrow) * 40 + lq * 8];
        #pragma unroll
        for (int i = 0; i < TM; i++)
            #pragma unroll
            for (int j = 0; j < TN; j++)
                acc[i][j] = __builtin_amdgcn_mfma_f32_16x16x32_bf16(af[i], bfr[j], acc[i][j], 0, 0, 0);
    }

    #pragma unroll
    for (int i = 0; i < TM; i++) {
        int gr0 = row0 + wm0 + i * 16 + lq * 4;
        #pragma unroll
        for (int j = 0; j < TN; j++) {
            int gc = col0 + wn0 + j * 16 + lrow;
            #pragma unroll
            for (int r = 0; r < 4; r++)
                Cf[(size_t)(gr0 + r) * N + gc] += acc[i][j][r];
        }
    }
}

// ---------------- causal depthwise conv (DC=4) + SiLU: 4 rows x 2 e per thread
__global__ void k_conv(const bf16_t* __restrict__ xz,
                       const float* __restrict__ conv_w, const float* __restrict__ conv_b,
                       bf16_t* __restrict__ xs, int layer) {
    int t = blockIdx.x * blockDim.x + threadIdx.x;   // (ROWS/4) * (ED/2)
    int ep = t % (ED_ / 2);
    int rb4 = t / (ED_ / 2);
    int e = ep * 2;
    int row0 = rb4 * 4;
    int b = row0 / L_, l0 = row0 % L_;
    float4 w0 = *(const float4*)(conv_w + ((size_t)layer * ED_ + e) * DC_);
    float4 w1 = *(const float4*)(conv_w + ((size_t)layer * ED_ + e + 1) * DC_);
    float bias0 = conv_b[layer * ED_ + e];
    float bias1 = conv_b[layer * ED_ + e + 1];
    const float wa0[4] = {w0.x, w0.y, w0.z, w0.w};
    const float wa1[4] = {w1.x, w1.y, w1.z, w1.w};
    float v0[7], v1[7];
    #pragma unroll
    for (int k = 0; k < 7; k++) {
        int ll = l0 - 3 + k;
        if (ll >= 0) {
            __hip_bfloat162 v = *(const __hip_bfloat162*)(xz + ((size_t)(b * L_ + ll)) * (2 * ED_) + e);
            v0[k] = b2f(v.x); v1[k] = b2f(v.y);
        } else { v0[k] = 0.f; v1[k] = 0.f; }
    }
    #pragma unroll
    for (int j = 0; j < 4; j++) {
        float acc0 = bias0, acc1 = bias1;
        #pragma unroll
        for (int k = 0; k < DC_; k++) {
            acc0 = fmaf(v0[j + k], wa0[k], acc0);
            acc1 = fmaf(v1[j + k], wa1[k], acc1);
        }
        __hip_bfloat162 o;
        o.x = __float2bfloat16(siluf(acc0));
        o.y = __float2bfloat16(siluf(acc1));
        *(__hip_bfloat162*)(xs + (size_t)(row0 + j) * ED_ + e) = o;
    }
}

// ---------------- fused xp-projection + dlt: xd[:,16:48] = xs @ xp_w;
// dlt = softplus(rk @ dt_w + dt_b), rk = (xs @ xp_w)[:, :16]. grid (1, 256).
__global__ __launch_bounds__(256) void k_gemm_xp_dlt(
        const bf16_t* __restrict__ A, const bf16_t* __restrict__ Bt,
        float* __restrict__ xd,
        const float* __restrict__ dt_w, const float* __restrict__ dt_b,
        bf16_t* __restrict__ dlt, int layer, int K) {
    constexpr int BM = 32, BN = 64, N = 48;
    __shared__ __align__(16) unsigned short sA[BM * 40];
    __shared__ __align__(16) unsigned short sB[BN * 40];
    __shared__ float s_rk[32][17];

    const int tid = threadIdx.x;
    const int wave = tid >> 6, lane = tid & 63;
    const int lrow = lane & 15, lq = lane >> 4;
    const int row0 = blockIdx.y * BM;
    const int wm0 = (wave >> 1) * 16;
    const int wn0 = (wave & 1) * 32;

    floatx4 acc[2];
    acc[0] = (floatx4)0.0f; acc[1] = (floatx4)0.0f;

    short8 ra, rb;
    const int NKB = K / 32;   // 16
    {
        int v = tid;
        if (v < BM * 4) {
            int m = v >> 2, ko = (v & 3) * 8;
            ra = *(const short8*)(A + (size_t)(row0 + m) * K + ko);
        }
        int n = v >> 2, ko = (v & 3) * 8;
        rb = (n < N) ? *(const short8*)(Bt + (size_t)n * K + ko) : (short8)0;
    }
    for (int kb = 0; kb < NKB; kb++) {
        __syncthreads();
        if (tid < BM * 4) {
            int m = tid >> 2, ko = (tid & 3) * 8;
            *(short8*)&sA[m * 40 + ko] = ra;
        }
        { int n = tid >> 2, ko = (tid & 3) * 8; *(short8*)&sB[n * 40 + ko] = rb; }
        __syncthreads();
        if (kb + 1 < NKB) {
            int k0 = (kb + 1) * 32;
            if (tid < BM * 4) {
                int m = tid >> 2, ko = (tid & 3) * 8;
                ra = *(const short8*)(A + (size_t)(row0 + m) * K + k0 + ko);
            }
            int n = tid >> 2, ko = (tid & 3) * 8;
            rb = (n < N) ? *(const short8*)(Bt + (size_t)n * K + k0 + ko) : (short8)0;
        }
        short8 af = *(const short8*)&sA[(wm0 + lrow) * 40 + lq * 8];
        short8 b0 = *(const short8*)&sB[(wn0 + lrow) * 40 + lq * 8];
        short8 b1 = *(const short8*)&sB[(wn0 + 16 + lrow) * 40 + lq * 8];
        acc[0] = __builtin_amdgcn_mfma_f32_16x16x32_bf16(af, b0, acc[0], 0, 0, 0);
        acc[1] = __builtin_amdgcn_mfma_f32_16x16x32_bf16(af, b1, acc[1], 0, 0, 0);
    }

    #pragma unroll
    for (int j = 0; j < 2; j++) {
        int gc = wn0 + j * 16 + lrow;
        #pragma unroll
        for (int r = 0; r < 4; r++) {
            int gr = row0 + wm0 + lq * 4 + r;
            if (gc >= 16 && gc < 48) xd[(size_t)gr * 48 + gc] = acc[j][r];
        }
    }
    if ((wave & 1) == 0) {
        #pragma unroll
        for (int r = 0; r < 4; r++)
            s_rk[wm0 + lq * 4 + r][lrow] = acc[0][r];
    }
    __syncthreads();

    const int e = 2 * tid;
    float2 wv[16];
    #pragma unroll
    for (int r = 0; r < RK_; r++)
        wv[r] = *(const float2*)(dt_w + ((size_t)layer * RK_ + r) * ED_ + e);
    float2 bb = *(const float2*)(dt_b + (size_t)layer * ED_ + e);
    #pragma unroll 4
    for (int row = 0; row < 32; row++) {
        float a0 = bb.x, a1 = bb.y;
        #pragma unroll
        for (int r = 0; r < RK_; r++) {
            float rk = s_rk[row][r];
            a0 = fmaf(rk, wv[r].x, a0);
            a1 = fmaf(rk, wv[r].y, a1);
        }
        __hip_bfloat162 o;
        o.x = __float2bfloat16(softplusf(a0));
        o.y = __float2bfloat16(softplusf(a1));
        *(__hip_bfloat162*)(dlt + (size_t)(row0 + row) * ED_ + e) = o;
    }
}

// ======== chunked selective scan, thread = (b, e, seg), 16 n-states in registers ====
// Geometric-A fast path (runtime-verified): A_n = (n+1)*A_0 => a_n = r^{n+1}.

__global__ __launch_bounds__(256) void k_scan1(
        const bf16_t* __restrict__ dlt, const bf16_t* __restrict__ xs,
        const float* __restrict__ xd,    // B at +16 (row stride 48)
        const float* __restrict__ A_log,
        float* __restrict__ aprod, float* __restrict__ hend, int layer) {
    __shared__ float s_B[64][16];
    const int te = threadIdx.x;
    const int bi = blockIdx.x;
    const int seg = bi & (SEG_ - 1);
    const int eh  = (bi >> 4) & 1;
    const int b   = bi >> 5;
    const int e   = eh * 256 + te;
    const int rowbase = b * L_ + seg * SLEN_;

    {   // stage B rows: 64 x 16 floats
        int flat = te * 4;
        int r = flat >> 4, c = flat & 15;
        *(float4*)&s_B[r][c] = *(const float4*)(xd + (size_t)(rowbase + r) * 48 + 16 + c);
    }

    float A[16];
    bool geo = true;
    {
        const float* ap = A_log + ((size_t)layer * ED_ + e) * NS_;
        #pragma unroll
        for (int n = 0; n < 16; n++) A[n] = -__expf(ap[n]);
        #pragma unroll
        for (int n = 1; n < 16; n++)
            geo = geo && (fabsf(A[n] - (float)(n + 1) * A[0]) <= 1e-3f * (float)(n + 1) * fabsf(A[0]));
    }

    float h[16];
    #pragma unroll
    for (int n = 0; n < 16; n++) h[n] = 0.f;
    float Pr = 1.0f;
    float P[16];
    #pragma unroll
    for (int n = 0; n < 16; n++) P[n] = 1.f;

    const bf16_t* dptr = dlt + (size_t)rowbase * ED_ + e;
    const bf16_t* xptr = xs  + (size_t)rowbase * ED_ + e;

    bf16_t dvb[8], xvb[8];
    #pragma unroll
    for (int j = 0; j < 8; j++) {
        dvb[j] = dptr[(size_t)j * ED_];
        xvb[j] = xptr[(size_t)j * ED_];
    }
    __syncthreads();

    for (int sub = 0; sub < 8; sub++) {
        bf16_t dnx[8], xnx[8];
        if (sub < 7) {
            const bf16_t* d2 = dptr + (size_t)(sub + 1) * 8 * ED_;
            const bf16_t* x2 = xptr + (size_t)(sub + 1) * 8 * ED_;
            #pragma unroll
            for (int j = 0; j < 8; j++) {
                dnx[j] = d2[(size_t)j * ED_];
                xnx[j] = x2[(size_t)j * ED_];
            }
        }
        if (geo) {
            #pragma unroll
            for (int j = 0; j < 8; j++) {
                int l = sub * 8 + j;
                float dv = b2f(dvb[j]), xv = b2f(xvb[j]);
                float dx = dv * xv;
                float Bv[16];
                #pragma unroll
                for (int q = 0; q < 4; q++)
                    *(float4*)&Bv[q * 4] = *(const float4*)&s_B[l][q * 4];
                float r = __expf(dv * A[0]);
                float r2 = r * r, r4 = r2 * r2;
                float a0 = r, a1 = r2, a2 = r2 * r, a3 = r4;
                #pragma unroll
                for (int q = 0; q < 4; q++) {
                    h[4*q+0] = fmaf(a0, h[4*q+0], dx * Bv[4*q+0]);
                    h[4*q+1] = fmaf(a1, h[4*q+1], dx * Bv[4*q+1]);
                    h[4*q+2] = fmaf(a2, h[4*q+2], dx * Bv[4*q+2]);
                    h[4*q+3] = fmaf(a3, h[4*q+3], dx * Bv[4*q+3]);
                    if (q < 3) { a0 *= r4; a1 *= r4; a2 *= r4; a3 *= r4; }
                }
                Pr *= r;
            }
        } else {
            #pragma unroll
            for (int j = 0; j < 8; j++) {
                int l = sub * 8 + j;
                float dv = b2f(dvb[j]), xv = b2f(xvb[j]);
                float dx = dv * xv;
                float Bv[16];
                #pragma unroll
                for (int q = 0; q < 4; q++)
                    *(float4*)&Bv[q * 4] = *(const float4*)&s_B[l][q * 4];
                #pragma unroll
                for (int n = 0; n < 16; n++) {
                    float a = __expf(dv * A[n]);
                    h[n] = fmaf(a, h[n], dx * Bv[n]);
                    P[n] *= a;
                }
            }
        }
        #pragma unroll
        for (int j = 0; j < 8; j++) { dvb[j] = dnx[j]; xvb[j] = xnx[j]; }
    }

    if (geo) {
        float p = Pr;
        #pragma unroll
        for (int n = 0; n < 16; n++) { P[n] = p; p *= Pr; }
    }
    #pragma unroll
    for (int n = 0; n < 16; n++) {
        size_t idx = ((((size_t)b * SEG_ + seg) << 4) + n) * ED_ + e;
        aprod[idx] = P[n];
        hend[idx]  = h[n];
    }
}

__global__ __launch_bounds__(256) void k_scan3(
        const bf16_t* __restrict__ dlt, const bf16_t* __restrict__ xs,
        const float* __restrict__ xd,    // B at +16, C at +32 (row stride 48)
        const bf16_t* __restrict__ xz,   // silu(z) at +ED
        const float* __restrict__ A_log, const float* __restrict__ Dp,
        const float* __restrict__ aprod, const float* __restrict__ hend,
        bf16_t* __restrict__ y, int layer) {
    __shared__ float s_BC[64][32];
    const int te = threadIdx.x;
    const int bi = blockIdx.x;
    const int seg = bi & (SEG_ - 1);
    const int eh  = (bi >> 4) & 1;
    const int b   = bi >> 5;
    const int e   = eh * 256 + te;
    const int rowbase = b * L_ + seg * SLEN_;

    {   // stage B|C rows: 64 x 32 floats
        int flat = te * 8;
        int r = flat >> 5, c = flat & 31;
        const float* src = xd + (size_t)(rowbase + r) * 48 + 16 + c;
        *(float4*)&s_BC[r][c]     = *(const float4*)(src);
        *(float4*)&s_BC[r][c + 4] = *(const float4*)(src + 4);
    }

    float A[16];
    bool geo = true;
    {
        const float* ap = A_log + ((size_t)layer * ED_ + e) * NS_;
        #pragma unroll
        for (int n = 0; n < 16; n++) A[n] = -__expf(ap[n]);
        #pragma unroll
        for (int n = 1; n < 16; n++)
            geo = geo && (fabsf(A[n] - (float)(n + 1) * A[0]) <= 1e-3f * (float)(n + 1) * fabsf(A[0]));
    }
    const float D = Dp[layer * ED_ + e];

    // cross-segment stitch (L2-hot)
    float h[16];
    #pragma unroll
    for (int n = 0; n < 16; n++) h[n] = 0.f;
    for (int s = 0; s < seg; s++) {
        const size_t pb = (((size_t)b * SEG_ + s) << 4) * ED_ + e;
        #pragma unroll
        for (int n = 0; n < 16; n++)
            h[n] = fmaf(aprod[pb + (size_t)n * ED_], h[n], hend[pb + (size_t)n * ED_]);
    }

    const bf16_t* dptr = dlt + (size_t)rowbase * ED_ + e;
    const bf16_t* xptr = xs  + (size_t)rowbase * ED_ + e;
    const bf16_t* zptr = xz  + (size_t)rowbase * (2 * ED_) + ED_ + e;
    bf16_t*       yptr = y   + (size_t)rowbase * ED_ + e;

    bf16_t dvb[8], xvb[8], zvb[8];
    #pragma unroll
    for (int j = 0; j < 8; j++) {
        dvb[j] = dptr[(size_t)j * ED_];
        xvb[j] = xptr[(size_t)j * ED_];
        zvb[j] = zptr[(size_t)j * (2 * ED_)];
    }
    __syncthreads();

    for (int sub = 0; sub < 8; sub++) {
        bf16_t dnx[8], xnx[8], znx[8];
        if (sub < 7) {
            const bf16_t* d2 = dptr + (size_t)(sub + 1) * 8 * ED_;
            const bf16_t* x2 = xptr + (size_t)(sub + 1) * 8 * ED_;
            const bf16_t* z2 = zptr + (size_t)(sub + 1) * 8 * (2 * ED_);
            #pragma unroll
            for (int j = 0; j < 8; j++) {
                dnx[j] = d2[(size_t)j * ED_];
                xnx[j] = x2[(size_t)j * ED_];
                znx[j] = z2[(size_t)j * (2 * ED_)];
            }
        }
        if (geo) {
            #pragma unroll
            for (int j = 0; j < 8; j++) {
                int l = sub * 8 + j;
                float dv = b2f(dvb[j]), xv = b2f(xvb[j]);
                float dx = dv * xv;
                float Bv[16], Cv[16];
                #pragma unroll
                for (int q = 0; q < 4; q++) {
                    *(float4*)&Bv[q * 4] = *(const float4*)&s_BC[l][q * 4];
                    *(float4*)&Cv[q * 4] = *(const float4*)&s_BC[l][16 + q * 4];
                }
                float r = __expf(dv * A[0]);
                float r2 = r * r, r4 = r2 * r2;
                float a0 = r, a1 = r2, a2 = r2 * r, a3 = r4;
                float y0 = D * xv, y1 = 0.f, y2 = 0.f, y3 = 0.f;
                #pragma unroll
                for (int q = 0; q < 4; q++) {
                    h[4*q+0] = fmaf(a0, h[4*q+0], dx * Bv[4*q+0]);
                    h[4*q+1] = fmaf(a1, h[4*q+1], dx * Bv[4*q+1]);
                    h[4*q+2] = fmaf(a2, h[4*q+2], dx * Bv[4*q+2]);
                    h[4*q+3] = fmaf(a3, h[4*q+3], dx * Bv[4*q+3]);
                    y0 = fmaf(Cv[4*q+0], h[4*q+0], y0);
                    y1 = fmaf(Cv[4*q+1], h[4*q+1], y1);
                    y2 = fmaf(Cv[4*q+2], h[4*q+2], y2);
                    y3 = fmaf(Cv[4*q+3], h[4*q+3], y3);
                    if (q < 3) { a0 *= r4; a1 *= r4; a2 *= r4; a3 *= r4; }
                }
                float yv = (y0 + y1) + (y2 + y3);
                yptr[(size_t)l * ED_] = __float2bfloat16(yv * b2f(zvb[j]));
            }
        } else {
            #pragma unroll
            for (int j = 0; j < 8; j++) {
                int l = sub * 8 + j;
                float dv = b2f(dvb[j]), xv = b2f(xvb[j]);
                float dx = dv * xv;
                float Bv[16], Cv[16];
                #pragma unroll
                for (int q = 0; q < 4; q++) {
                    *(float4*)&Bv[q * 4] = *(const float4*)&s_BC[l][q * 4];
                    *(float4*)&Cv[q * 4] = *(const float4*)&s_BC[l][16 + q * 4];
                }
                float y0 = D * xv, y1 = 0.f, y2 = 0.f, y3 = 0.f;
                #pragma unroll
                for (int n = 0; n < 16; n++) {
                    float a = __expf(dv * A[n]);
                    h[n] = fmaf(a, h[n], dx * Bv[n]);
                    float t = Cv[n] * h[n];
                    if ((n & 3) == 0) y0 += t;
                    else if ((n & 3) == 1) y1 += t;
                    else if ((n & 3) == 2) y2 += t;
                    else y3 += t;
                }
                float yv = (y0 + y1) + (y2 + y3);
                yptr[(size_t)l * ED_] = __float2bfloat16(yv * b2f(zvb[j]));
            }
        }
        #pragma unroll
        for (int j = 0; j < 8; j++) { dvb[j] = dnx[j]; xvb[j] = xnx[j]; zvb[j] = znx[j]; }
    }
}

// ---------------- final LN + head; wave-per-row, 4 rows/block
__global__ void k_final(const float* __restrict__ x,
                        const float* __restrict__ fg, const float* __restrict__ fb,
                        const float* __restrict__ hw, const float* __restrict__ hb,
                        float* __restrict__ out) {
    int lane = threadIdx.x & 63, w = threadIdx.x >> 6;
    int row = blockIdx.x * 4 + w;
    const float* xr = x + (size_t)row * DM_;
    float v[4];
    #pragma unroll
    for (int k = 0; k < 4; k++) v[k] = xr[lane + 64 * k];
    float s = (v[0] + v[1]) + (v[2] + v[3]);
    float q = (v[0] * v[0] + v[1] * v[1]) + (v[2] * v[2] + v[3] * v[3]);
    #pragma unroll
    for (int off = 32; off > 0; off >>= 1) {
        s += __shfl_xor(s, off, 64);
        q += __shfl_xor(q, off, 64);
    }
    float mean = s * (1.0f / DM_);
    float var = q * (1.0f / DM_) - mean * mean;
    float rstd = rsqrtf(var + 1e-5f);
    float s0 = 0.f, s1 = 0.f;
    #pragma unroll
    for (int k = 0; k < 4; k++) {
        int c = lane + 64 * k;
        float xf = (v[k] - mean) * rstd * fg[c] + fb[c];
        s0 += xf * hw[c * Q_ + 0];
        s1 += xf * hw[c * Q_ + 1];
    }
    #pragma unroll
    for (int off = 32; off > 0; off >>= 1) {
        s0 += __shfl_xor(s0, off, 64);
        s1 += __shfl_xor(s1, off, 64);
    }
    if (lane == 0) {
        out[row * Q_ + 0] = s0 + hb[0];
        out[row * Q_ + 1] = s1 + hb[1];
    }
}

extern "C" void kernel_launch(void* const* d_in, const int* in_sizes, int n_in,
                              void* d_out, int out_size, void* d_ws, size_t ws_size,
                              hipStream_t stream) {
    const int*   tokens    = (const int*)d_in[0];
    const float* T         = (const float*)d_in[1];
    const float* tok_embed = (const float*)d_in[2];
    const float* pos_embed = (const float*)d_in[3];
    const float* tw1       = (const float*)d_in[4];
    const float* tb1       = (const float*)d_in[5];
    const float* tw2       = (const float*)d_in[6];
    const float* tb2       = (const float*)d_in[7];
    const float* ag        = (const float*)d_in[8];
    const float* ab        = (const float*)d_in[9];
    const float* apw       = (const float*)d_in[10];
    const float* apb       = (const float*)d_in[11];
    const float* in_w      = (const float*)d_in[12];
    const float* conv_w    = (const float*)d_in[13];
    const float* conv_b    = (const float*)d_in[14];
    const float* xp_w      = (const float*)d_in[15];
    const float* dt_w      = (const float*)d_in[16];
    const float* dt_b      = (const float*)d_in[17];
    const float* A_log     = (const float*)d_in[18];
    const float* Dp        = (const float*)d_in[19];
    const float* out_w     = (const float*)d_in[20];
    const float* fg        = (const float*)d_in[21];
    const float* fb        = (const float*)d_in[22];
    const float* hw        = (const float*)d_in[23];
    const float* hb        = (const float*)d_in[24];
    float* out = (float*)d_out;

    const int ROWS = B_ * L_;   // 8192

    char* p = (char*)d_ws;
    float*  x      = (float*)p;   p += (size_t)ROWS * DM_ * 4;
    bf16_t* xz     = (bf16_t*)p;  p += (size_t)ROWS * 2 * ED_ * 2;
    bf16_t* xs     = (bf16_t*)p;  p += (size_t)ROWS * ED_ * 2;
    float*  xd     = (float*)p;   p += (size_t)ROWS * 48 * 4;
    bf16_t* dlt    = (bf16_t*)p;  p += (size_t)ROWS * ED_ * 2;
    bf16_t* y      = (bf16_t*)p;  p += (size_t)ROWS * ED_ * 2;
    float*  ss     = (float*)p;   p += (size_t)NL_ * B_ * 2 * DM_ * 4;
    float*  aprod  = (float*)p;   p += (size_t)B_ * SEG_ * NS_ * ED_ * 4;  // 4 MB
    float*  hendb  = (float*)p;   p += (size_t)B_ * SEG_ * NS_ * ED_ * 4;  // 4 MB
    bf16_t* in_wT  = (bf16_t*)p;  p += (size_t)NL_ * 2 * ED_ * DM_ * 2;
    bf16_t* xp_wT  = (bf16_t*)p;  p += (size_t)NL_ * 48 * ED_ * 2;
    bf16_t* out_wT = (bf16_t*)p;  p += (size_t)NL_ * DM_ * ED_ * 2;

    k_transpose_all<<<dim3(32, 16, 12), 256, 0, stream>>>(
        in_w, xp_w, out_w, in_wT, xp_wT, out_wT);
    k_prep<<<dim3(B_, NL_), 2 * DM_, 0, stream>>>(T, tw1, tb1, tw2, tb2, apw, apb, ss);
    k_embed<<<ROWS, DM_, 0, stream>>>(tokens, tok_embed, pos_embed, x);

    for (int i = 0; i < NL_; i++) {
        // xz = mod(LN(x)) @ in_w[i]  (LN fused into A-staging; silu on z half)
        k_ln_gemm_in<<<dim3(2 * ED_ / 128, ROWS / 128), 256, 0, stream>>>(
            x, ag, ab, ss, in_wT + (size_t)i * 2 * ED_ * DM_, xz, i);
        // xs = silu(conv(xz))
        k_conv<<<(ROWS / 4) * (ED_ / 2) / 256, 256, 0, stream>>>(xz, conv_w, conv_b, xs, i);
        // xd[:,16:48] = xs @ xp_w[i]; dlt = softplus(rk @ dt_w + dt_b)
        k_gemm_xp_dlt<<<dim3(1, ROWS / 32), 256, 0, stream>>>(
            xs, xp_wT + (size_t)i * 48 * ED_, xd, dt_w, dt_b, dlt, i, ED_);
        // chunked scan
        k_scan1<<<B_ * 2 * SEG_, 256, 0, stream>>>(dlt, xs, xd, A_log, aprod, hendb, i);
        k_scan3<<<B_ * 2 * SEG_, 256, 0, stream>>>(
            dlt, xs, xd, xz, A_log, Dp, aprod, hendb, y, i);
        // x += y @ out_w[i]
        k_mfma_gemm_acc<128, 64><<<dim3(DM_ / 64, ROWS / 128), 256, 0, stream>>>(
            y, out_wT + (size_t)i * DM_ * ED_, x, ROWS, DM_, ED_);
    }

    k_final<<<ROWS / 4, 256, 0, stream>>>(x, fg, fb, hw, hb, out);
}

// Round 15
// 582.702 us; speedup vs baseline: 1.0448x; 1.0448x over previous
//
#include <hip/hip_runtime.h>
#include <hip/hip_bf16.h>
#include <math.h>

#define B_   8
#define L_   1024
#define DM_  256
#define NL_  4
#define ED_  512
#define NS_  16
#define DC_  4
#define RK_  16
#define CD_  64
#define Q_   2

#define SEG_  16    // segments along L
#define SLEN_ 64    // L_/SEG_

typedef __hip_bfloat16 bf16_t;
typedef __attribute__((ext_vector_type(8))) short short8;
typedef __attribute__((ext_vector_type(4))) float floatx4;

__device__ __forceinline__ float geluf(float x) {
    return 0.5f * x * (1.0f + erff(x * 0.70710678118654752f));
}
__device__ __forceinline__ float siluf(float x) {
    return x / (1.0f + __expf(-x));
}
__device__ __forceinline__ float softplusf(float x) {
    return (x > 20.0f) ? x : log1pf(expf(x));
}
__device__ __forceinline__ float b2f(bf16_t v) { return __bfloat162float(v); }
__device__ __forceinline__ float bits2f(short u) {
    return __uint_as_float(((unsigned)(unsigned short)u) << 16);
}
__device__ __forceinline__ short f2bfbits(float v) {
    return __builtin_bit_cast(short, __float2bfloat16(v));
}

// ---------------- one-shot batched weight transpose + bf16 convert
__global__ void k_transpose_all(const float* __restrict__ in_w,
                                const float* __restrict__ xp_w,
                                const float* __restrict__ out_w,
                                bf16_t* __restrict__ in_wT,
                                bf16_t* __restrict__ xp_wT,
                                bf16_t* __restrict__ out_wT) {
    __shared__ float t[32][33];
    int z = blockIdx.z;
    int which = z >> 2, layer = z & 3;
    const float* src; bf16_t* dst; int R, C;
    if (which == 0)      { R = DM_; C = 2 * ED_; src = in_w;  dst = in_wT;  }
    else if (which == 1) { R = ED_; C = 48;      src = xp_w;  dst = xp_wT;  }
    else                 { R = ED_; C = DM_;     src = out_w; dst = out_wT; }
    src += (size_t)layer * R * C;
    dst += (size_t)layer * R * C;
    int c0 = blockIdx.x * 32, r0 = blockIdx.y * 32;
    if (c0 >= C || r0 >= R) return;
    int tx = threadIdx.x & 31, ty = threadIdx.x >> 5;   // 32 x 8
    #pragma unroll
    for (int i = 0; i < 32; i += 8) {
        int r = r0 + ty + i, c = c0 + tx;
        t[ty + i][tx] = (r < R && c < C) ? src[(size_t)r * C + c] : 0.f;
    }
    __syncthreads();
    #pragma unroll
    for (int i = 0; i < 32; i += 8) {
        int c = c0 + ty + i, r = r0 + tx;
        if (c < C && r < R) dst[(size_t)c * R + r] = __float2bfloat16(t[tx][ty + i]);
    }
}

// ---------------- embed
__global__ void k_embed(const int* __restrict__ tokens,
                        const float* __restrict__ tok_embed,
                        const float* __restrict__ pos_embed,
                        float* __restrict__ x) {
    int row = blockIdx.x;
    int d = threadIdx.x;
    int b = row / L_, l = row % L_;
    float v = pos_embed[l * DM_ + d];
    if (l > 0) {
        int tok = tokens[b * L_ + l - 1];
        v += tok_embed[tok * DM_ + d];
    }
    x[row * DM_ + d] = v;
}

// ---------------- conditioning + all-layer adaLN params in one launch
__global__ void k_prep(const float* __restrict__ T,
                       const float* __restrict__ tw1, const float* __restrict__ tb1,
                       const float* __restrict__ tw2, const float* __restrict__ tb2,
                       const float* __restrict__ apw, const float* __restrict__ apb,
                       float* __restrict__ ss) {
    __shared__ float h[CD_], cnd[CD_];
    int b = blockIdx.x, layer = blockIdx.y;
    int j = threadIdx.x;
    if (j < CD_) h[j] = geluf(T[b] * tw1[j] + tb1[j]);
    __syncthreads();
    if (j < CD_) {
        float acc = tb2[j];
        #pragma unroll
        for (int c = 0; c < CD_; c++) acc += h[c] * tw2[c * CD_ + j];
        cnd[j] = acc;
    }
    __syncthreads();
    const float* w = apw + (size_t)layer * CD_ * 2 * DM_;
    float acc = apb[layer * 2 * DM_ + j];
    #pragma unroll
    for (int c = 0; c < CD_; c++) acc += cnd[c] * w[c * 2 * DM_ + j];
    ss[((size_t)layer * B_ + b) * 2 * DM_ + j] = acc;
}

// ---------------- fused LN+adaLN + in-projection MFMA GEMM
// xz[8192][1024] = mod(LN(x)) @ in_wT^T, silu applied to cols >= ED_.
// 1D grid, ROW-TILE FASTEST: bi&63 = row tile, bi>>6 = col tile. The 8 col
// blocks of one row tile differ by bi multiples of 64 == 0 mod 8 XCDs ->
// same XCD -> x row-tile fetched into exactly one L2 (kills the 8x over-fetch).
__global__ __launch_bounds__(256) void k_ln_gemm_in(
        const float* __restrict__ x,
        const float* __restrict__ ag, const float* __restrict__ ab,
        const float* __restrict__ ss,
        const bf16_t* __restrict__ Bt,
        bf16_t* __restrict__ xz, int layer) {
    constexpr int BM = 128, BN = 128, K = 256, N = 2 * ED_;
    constexpr int TM = 4, TN = 4;
    __shared__ __align__(16) unsigned short sA[BM * 40];
    __shared__ __align__(16) unsigned short sB[BN * 40];
    __shared__ float s_mr[BM][2];
    __shared__ float s_prm[4 * DM_];   // g | b | (1+sc) | sh

    const int tid = threadIdx.x;
    const int wave = tid >> 6, lane = tid & 63;
    const int lrow = lane & 15, lq = lane >> 4;
    const int bi = blockIdx.x;
    const int row0 = (bi & 63) * BM, col0 = (bi >> 6) * BN;
    const int b = row0 / L_;
    const int wm0 = (wave >> 1) * 64, wn0 = (wave & 1) * 64;

    {
        s_prm[tid]       = ag[layer * DM_ + tid];
        s_prm[256 + tid] = ab[layer * DM_ + tid];
        const float* ssl = ss + ((size_t)layer * B_ + b) * 2 * DM_;
        s_prm[512 + tid] = 1.0f + ssl[tid];
        s_prm[768 + tid] = ssl[DM_ + tid];
    }
    {
        int r = tid >> 1, half = tid & 1;
        const float* xr = x + (size_t)(row0 + r) * K + half * 128;
        float s = 0.f, q = 0.f;
        #pragma unroll
        for (int i = 0; i < 32; i++) {
            float4 v = *(const float4*)(xr + i * 4);
            s += (v.x + v.y) + (v.z + v.w);
            q += (v.x * v.x + v.y * v.y) + (v.z * v.z + v.w * v.w);
        }
        s += __shfl_xor(s, 1, 64);
        q += __shfl_xor(q, 1, 64);
        if (!half) {
            float mean = s * (1.0f / K);
            float var = q * (1.0f / K) - mean * mean;
            s_mr[r][0] = mean;
            s_mr[r][1] = rsqrtf(var + 1e-5f);
        }
    }

    floatx4 acc[TM][TN];
    #pragma unroll
    for (int i = 0; i < TM; i++)
        #pragma unroll
        for (int j = 0; j < TN; j++) acc[i][j] = (floatx4)0.0f;

    float4 raf[2][2];
    short8 rb[2];
    const int NKB = K / 32;   // 8
    #pragma unroll
    for (int i = 0; i < 2; i++) {
        int v = tid + i * 256; int m = v >> 2, ko = (v & 3) * 8;
        raf[i][0] = *(const float4*)(x + (size_t)(row0 + m) * K + ko);
        raf[i][1] = *(const float4*)(x + (size_t)(row0 + m) * K + ko + 4);
    }
    #pragma unroll
    for (int i = 0; i < 2; i++) {
        int v = tid + i * 256; int n = v >> 2, ko = (v & 3) * 8;
        rb[i] = *(const short8*)(Bt + (size_t)(col0 + n) * K + ko);
    }

    for (int kb = 0; kb < NKB; kb++) {
        __syncthreads();
        #pragma unroll
        for (int i = 0; i < 2; i++) {
            int v = tid + i * 256; int m = v >> 2, ko = (v & 3) * 8;
            int c0 = kb * 32 + ko;
            float mean = s_mr[m][0], rstd = s_mr[m][1];
            float av[8] = {raf[i][0].x, raf[i][0].y, raf[i][0].z, raf[i][0].w,
                           raf[i][1].x, raf[i][1].y, raf[i][1].z, raf[i][1].w};
            short8 o;
            #pragma unroll
            for (int j = 0; j < 8; j++) {
                int c = c0 + j;
                float ln = (av[j] - mean) * rstd * s_prm[c] + s_prm[256 + c];
                o[j] = f2bfbits(s_prm[512 + c] * ln + s_prm[768 + c]);
            }
            *(short8*)&sA[m * 40 + ko] = o;
        }
        #pragma unroll
        for (int i = 0; i < 2; i++) {
            int v = tid + i * 256; int n = v >> 2, ko = (v & 3) * 8;
            *(short8*)&sB[n * 40 + ko] = rb[i];
        }
        __syncthreads();
        if (kb + 1 < NKB) {
            int k0 = (kb + 1) * 32;
            #pragma unroll
            for (int i = 0; i < 2; i++) {
                int v = tid + i * 256; int m = v >> 2, ko = (v & 3) * 8;
                raf[i][0] = *(const float4*)(x + (size_t)(row0 + m) * K + k0 + ko);
                raf[i][1] = *(const float4*)(x + (size_t)(row0 + m) * K + k0 + ko + 4);
            }
            #pragma unroll
            for (int i = 0; i < 2; i++) {
                int v = tid + i * 256; int n = v >> 2, ko = (v & 3) * 8;
                rb[i] = *(const short8*)(Bt + (size_t)(col0 + n) * K + k0 + ko);
            }
        }
        short8 af[TM], bfr[TN];
        #pragma unroll
        for (int i = 0; i < TM; i++)
            af[i] = *(const short8*)&sA[(wm0 + i * 16 + lrow) * 40 + lq * 8];
        #pragma unroll
        for (int j = 0; j < TN; j++)
            bfr[j] = *(const short8*)&sB[(wn0 + j * 16 + lrow) * 40 + lq * 8];
        #pragma unroll
        for (int i = 0; i < TM; i++)
            #pragma unroll
            for (int j = 0; j < TN; j++)
                acc[i][j] = __builtin_amdgcn_mfma_f32_16x16x32_bf16(af[i], bfr[j], acc[i][j], 0, 0, 0);
    }

    #pragma unroll
    for (int i = 0; i < TM; i++) {
        int gr0 = row0 + wm0 + i * 16 + lq * 4;
        #pragma unroll
        for (int j = 0; j < TN; j++) {
            int gc = col0 + wn0 + j * 16 + lrow;
            #pragma unroll
            for (int r = 0; r < 4; r++) {
                float val = acc[i][j][r];
                if (gc >= ED_) val = siluf(val);
                xz[(size_t)(gr0 + r) * N + gc] = __float2bfloat16(val);
            }
        }
    }
}

// ---------------- MFMA bf16 GEMM (out-projection): C[M,N] += A[M,K] @ Bt[N,K]^T
// 1D grid, row-tile fastest (XCD swizzle): rt = bi % nrt, ct = bi / nrt.
template<int BM, int BN>
__global__ __launch_bounds__(256) void k_mfma_gemm_acc(
        const bf16_t* __restrict__ A, const bf16_t* __restrict__ Bt,
        float* __restrict__ Cf, int M, int N, int K) {
    constexpr int TM = BM / 32, TN = BN / 32;
    constexpr int VA = BM * 4, VB = BN * 4;
    constexpr int NA = (VA + 255) / 256;
    constexpr int NB = (VB + 255) / 256;
    __shared__ __align__(16) unsigned short sA[BM * 40];
    __shared__ __align__(16) unsigned short sB[BN * 40];

    const int tid = threadIdx.x;
    const int wave = tid >> 6, lane = tid & 63;
    const int lrow = lane & 15, lq = lane >> 4;
    const int nrt = M / BM;
    const int bi = blockIdx.x;
    const int row0 = (bi % nrt) * BM, col0 = (bi / nrt) * BN;
    const int wm0 = (wave >> 1) * (BM / 2);
    const int wn0 = (wave & 1) * (BN / 2);

    floatx4 acc[TM][TN];
    #pragma unroll
    for (int i = 0; i < TM; i++)
        #pragma unroll
        for (int j = 0; j < TN; j++) acc[i][j] = (floatx4)0.0f;

    short8 ra[NA], rb[NB];
    const int NKB = K / 32;

    #pragma unroll
    for (int i = 0; i < NA; i++) {
        int v = tid + i * 256;
        if (v < VA) {
            int m = v >> 2, ko = (v & 3) * 8;
            ra[i] = *(const short8*)(A + (size_t)(row0 + m) * K + ko);
        }
    }
    #pragma unroll
    for (int i = 0; i < NB; i++) {
        int v = tid + i * 256;
        if (v < VB) {
            int n = v >> 2, ko = (v & 3) * 8;
            rb[i] = *(const short8*)(Bt + (size_t)(col0 + n) * K + ko);
        }
    }

    for (int kb = 0; kb < NKB; kb++) {
        __syncthreads();
        #pragma unroll
        for (int i = 0; i < NA; i++) {
            int v = tid + i * 256;
            if (v < VA) {
                int m = v >> 2, ko = (v & 3) * 8;
                *(short8*)&sA[m * 40 + ko] = ra[i];
            }
        }
        #pragma unroll
        for (int i = 0; i < NB; i++) {
            int v = tid + i * 256;
            if (v < VB) {
                int n = v >> 2, ko = (v & 3) * 8;
                *(short8*)&sB[n * 40 + ko] = rb[i];
            }
        }
        __syncthreads();
        if (kb + 1 < NKB) {
            int k0 = (kb + 1) * 32;
            #pragma unroll
            for (int i = 0; i < NA; i++) {
                int v = tid + i * 256;
                if (v < VA) {
                    int m = v >> 2, ko = (v & 3) * 8;
                    ra[i] = *(const short8*)(A + (size_t)(row0 + m) * K + k0 + ko);
                }
            }
            #pragma unroll
            for (int i = 0; i < NB; i++) {
                int v = tid + i * 256;
                if (v < VB) {
                    int n = v >> 2, ko = (v & 3) * 8;
                    rb[i] = *(const short8*)(Bt + (size_t)(col0 + n) * K + k0 + ko);
                }
            }
        }
        short8 af[TM], bfr[TN];
        #pragma unroll
        for (int i = 0; i < TM; i++)
            af[i] = *(const short8*)&sA[(wm0 + i * 16 + lrow) * 40 + lq * 8];
        #pragma unroll
        for (int j = 0; j < TN; j++)
            bfr[j] = *(const short8*)&sB[(wn0 + j * 16 + lrow) * 40 + lq * 8];
        #pragma unroll
        for (int i = 0; i < TM; i++)
            #pragma unroll
            for (int j = 0; j < TN; j++)
                acc[i][j] = __builtin_amdgcn_mfma_f32_16x16x32_bf16(af[i], bfr[j], acc[i][j], 0, 0, 0);
    }

    #pragma unroll
    for (int i = 0; i < TM; i++) {
        int gr0 = row0 + wm0 + i * 16 + lq * 4;
        #pragma unroll
        for (int j = 0; j < TN; j++) {
            int gc = col0 + wn0 + j * 16 + lrow;
            #pragma unroll
            for (int r = 0; r < 4; r++)
                Cf[(size_t)(gr0 + r) * N + gc] += acc[i][j][r];
        }
    }
}

// ---------------- causal depthwise conv (DC=4) + SiLU: 4 rows x 2 e per thread
__global__ void k_conv(const bf16_t* __restrict__ xz,
                       const float* __restrict__ conv_w, const float* __restrict__ conv_b,
                       bf16_t* __restrict__ xs, int layer) {
    int t = blockIdx.x * blockDim.x + threadIdx.x;   // (ROWS/4) * (ED/2)
    int ep = t % (ED_ / 2);
    int rb4 = t / (ED_ / 2);
    int e = ep * 2;
    int row0 = rb4 * 4;
    int b = row0 / L_, l0 = row0 % L_;
    float4 w0 = *(const float4*)(conv_w + ((size_t)layer * ED_ + e) * DC_);
    float4 w1 = *(const float4*)(conv_w + ((size_t)layer * ED_ + e + 1) * DC_);
    float bias0 = conv_b[layer * ED_ + e];
    float bias1 = conv_b[layer * ED_ + e + 1];
    const float wa0[4] = {w0.x, w0.y, w0.z, w0.w};
    const float wa1[4] = {w1.x, w1.y, w1.z, w1.w};
    float v0[7], v1[7];
    #pragma unroll
    for (int k = 0; k < 7; k++) {
        int ll = l0 - 3 + k;
        if (ll >= 0) {
            __hip_bfloat162 v = *(const __hip_bfloat162*)(xz + ((size_t)(b * L_ + ll)) * (2 * ED_) + e);
            v0[k] = b2f(v.x); v1[k] = b2f(v.y);
        } else { v0[k] = 0.f; v1[k] = 0.f; }
    }
    #pragma unroll
    for (int j = 0; j < 4; j++) {
        float acc0 = bias0, acc1 = bias1;
        #pragma unroll
        for (int k = 0; k < DC_; k++) {
            acc0 = fmaf(v0[j + k], wa0[k], acc0);
            acc1 = fmaf(v1[j + k], wa1[k], acc1);
        }
        __hip_bfloat162 o;
        o.x = __float2bfloat16(siluf(acc0));
        o.y = __float2bfloat16(siluf(acc1));
        *(__hip_bfloat162*)(xs + (size_t)(row0 + j) * ED_ + e) = o;
    }
}

// ---------------- fused xp-projection + dlt: xd[:,16:48] = xs @ xp_w;
// dlt = softplus(rk @ dt_w + dt_b), rk = (xs @ xp_w)[:, :16]. grid (1, 256).
__global__ __launch_bounds__(256) void k_gemm_xp_dlt(
        const bf16_t* __restrict__ A, const bf16_t* __restrict__ Bt,
        float* __restrict__ xd,
        const float* __restrict__ dt_w, const float* __restrict__ dt_b,
        bf16_t* __restrict__ dlt, int layer, int K) {
    constexpr int BM = 32, BN = 64, N = 48;
    __shared__ __align__(16) unsigned short sA[BM * 40];
    __shared__ __align__(16) unsigned short sB[BN * 40];
    __shared__ float s_rk[32][17];

    const int tid = threadIdx.x;
    const int wave = tid >> 6, lane = tid & 63;
    const int lrow = lane & 15, lq = lane >> 4;
    const int row0 = blockIdx.y * BM;
    const int wm0 = (wave >> 1) * 16;
    const int wn0 = (wave & 1) * 32;

    floatx4 acc[2];
    acc[0] = (floatx4)0.0f; acc[1] = (floatx4)0.0f;

    short8 ra, rb;
    const int NKB = K / 32;   // 16
    {
        int v = tid;
        if (v < BM * 4) {
            int m = v >> 2, ko = (v & 3) * 8;
            ra = *(const short8*)(A + (size_t)(row0 + m) * K + ko);
        }
        int n = v >> 2, ko = (v & 3) * 8;
        rb = (n < N) ? *(const short8*)(Bt + (size_t)n * K + ko) : (short8)0;
    }
    for (int kb = 0; kb < NKB; kb++) {
        __syncthreads();
        if (tid < BM * 4) {
            int m = tid >> 2, ko = (tid & 3) * 8;
            *(short8*)&sA[m * 40 + ko] = ra;
        }
        { int n = tid >> 2, ko = (tid & 3) * 8; *(short8*)&sB[n * 40 + ko] = rb; }
        __syncthreads();
        if (kb + 1 < NKB) {
            int k0 = (kb + 1) * 32;
            if (tid < BM * 4) {
                int m = tid >> 2, ko = (tid & 3) * 8;
                ra = *(const short8*)(A + (size_t)(row0 + m) * K + k0 + ko);
            }
            int n = tid >> 2, ko = (tid & 3) * 8;
            rb = (n < N) ? *(const short8*)(Bt + (size_t)n * K + k0 + ko) : (short8)0;
        }
        short8 af = *(const short8*)&sA[(wm0 + lrow) * 40 + lq * 8];
        short8 b0 = *(const short8*)&sB[(wn0 + lrow) * 40 + lq * 8];
        short8 b1 = *(const short8*)&sB[(wn0 + 16 + lrow) * 40 + lq * 8];
        acc[0] = __builtin_amdgcn_mfma_f32_16x16x32_bf16(af, b0, acc[0], 0, 0, 0);
        acc[1] = __builtin_amdgcn_mfma_f32_16x16x32_bf16(af, b1, acc[1], 0, 0, 0);
    }

    #pragma unroll
    for (int j = 0; j < 2; j++) {
        int gc = wn0 + j * 16 + lrow;
        #pragma unroll
        for (int r = 0; r < 4; r++) {
            int gr = row0 + wm0 + lq * 4 + r;
            if (gc >= 16 && gc < 48) xd[(size_t)gr * 48 + gc] = acc[j][r];
        }
    }
    if ((wave & 1) == 0) {
        #pragma unroll
        for (int r = 0; r < 4; r++)
            s_rk[wm0 + lq * 4 + r][lrow] = acc[0][r];
    }
    __syncthreads();

    const int e = 2 * tid;
    float2 wv[16];
    #pragma unroll
    for (int r = 0; r < RK_; r++)
        wv[r] = *(const float2*)(dt_w + ((size_t)layer * RK_ + r) * ED_ + e);
    float2 bb = *(const float2*)(dt_b + (size_t)layer * ED_ + e);
    #pragma unroll 4
    for (int row = 0; row < 32; row++) {
        float a0 = bb.x, a1 = bb.y;
        #pragma unroll
        for (int r = 0; r < RK_; r++) {
            float rk = s_rk[row][r];
            a0 = fmaf(rk, wv[r].x, a0);
            a1 = fmaf(rk, wv[r].y, a1);
        }
        __hip_bfloat162 o;
        o.x = __float2bfloat16(softplusf(a0));
        o.y = __float2bfloat16(softplusf(a1));
        *(__hip_bfloat162*)(dlt + (size_t)(row0 + row) * ED_ + e) = o;
    }
}

// ======== chunked selective scan, thread = (b, e, seg), 16 n-states in registers ====
// Geometric-A fast path (runtime-verified): A_n = (n+1)*A_0 => a_n = r^{n+1}.

__global__ __launch_bounds__(256) void k_scan1(
        const bf16_t* __restrict__ dlt, const bf16_t* __restrict__ xs,
        const float* __restrict__ xd,    // B at +16 (row stride 48)
        const float* __restrict__ A_log,
        float* __restrict__ aprod, float* __restrict__ hend, int layer) {
    __shared__ float s_B[64][16];
    const int te = threadIdx.x;
    const int bi = blockIdx.x;
    const int seg = bi & (SEG_ - 1);
    const int eh  = (bi >> 4) & 1;
    const int b   = bi >> 5;
    const int e   = eh * 256 + te;
    const int rowbase = b * L_ + seg * SLEN_;

    {   // stage B rows: 64 x 16 floats
        int flat = te * 4;
        int r = flat >> 4, c = flat & 15;
        *(float4*)&s_B[r][c] = *(const float4*)(xd + (size_t)(rowbase + r) * 48 + 16 + c);
    }

    float A[16];
    bool geo = true;
    {
        const float* ap = A_log + ((size_t)layer * ED_ + e) * NS_;
        #pragma unroll
        for (int n = 0; n < 16; n++) A[n] = -__expf(ap[n]);
        #pragma unroll
        for (int n = 1; n < 16; n++)
            geo = geo && (fabsf(A[n] - (float)(n + 1) * A[0]) <= 1e-3f * (float)(n + 1) * fabsf(A[0]));
    }

    float h[16];
    #pragma unroll
    for (int n = 0; n < 16; n++) h[n] = 0.f;
    float Pr = 1.0f;
    float P[16];
    #pragma unroll
    for (int n = 0; n < 16; n++) P[n] = 1.f;

    const bf16_t* dptr = dlt + (size_t)rowbase * ED_ + e;
    const bf16_t* xptr = xs  + (size_t)rowbase * ED_ + e;

    bf16_t dvb[8], xvb[8];
    #pragma unroll
    for (int j = 0; j < 8; j++) {
        dvb[j] = dptr[(size_t)j * ED_];
        xvb[j] = xptr[(size_t)j * ED_];
    }
    __syncthreads();

    for (int sub = 0; sub < 8; sub++) {
        bf16_t dnx[8], xnx[8];
        if (sub < 7) {
            const bf16_t* d2 = dptr + (size_t)(sub + 1) * 8 * ED_;
            const bf16_t* x2 = xptr + (size_t)(sub + 1) * 8 * ED_;
            #pragma unroll
            for (int j = 0; j < 8; j++) {
                dnx[j] = d2[(size_t)j * ED_];
                xnx[j] = x2[(size_t)j * ED_];
            }
        }
        if (geo) {
            #pragma unroll
            for (int j = 0; j < 8; j++) {
                int l = sub * 8 + j;
                float dv = b2f(dvb[j]), xv = b2f(xvb[j]);
                float dx = dv * xv;
                float Bv[16];
                #pragma unroll
                for (int q = 0; q < 4; q++)
                    *(float4*)&Bv[q * 4] = *(const float4*)&s_B[l][q * 4];
                float r = __expf(dv * A[0]);
                float r2 = r * r, r4 = r2 * r2;
                float a0 = r, a1 = r2, a2 = r2 * r, a3 = r4;
                #pragma unroll
                for (int q = 0; q < 4; q++) {
                    h[4*q+0] = fmaf(a0, h[4*q+0], dx * Bv[4*q+0]);
                    h[4*q+1] = fmaf(a1, h[4*q+1], dx * Bv[4*q+1]);
                    h[4*q+2] = fmaf(a2, h[4*q+2], dx * Bv[4*q+2]);
                    h[4*q+3] = fmaf(a3, h[4*q+3], dx * Bv[4*q+3]);
                    if (q < 3) { a0 *= r4; a1 *= r4; a2 *= r4; a3 *= r4; }
                }
                Pr *= r;
            }
        } else {
            #pragma unroll
            for (int j = 0; j < 8; j++) {
                int l = sub * 8 + j;
                float dv = b2f(dvb[j]), xv = b2f(xvb[j]);
                float dx = dv * xv;
                float Bv[16];
                #pragma unroll
                for (int q = 0; q < 4; q++)
                    *(float4*)&Bv[q * 4] = *(const float4*)&s_B[l][q * 4];
                #pragma unroll
                for (int n = 0; n < 16; n++) {
                    float a = __expf(dv * A[n]);
                    h[n] = fmaf(a, h[n], dx * Bv[n]);
                    P[n] *= a;
                }
            }
        }
        #pragma unroll
        for (int j = 0; j < 8; j++) { dvb[j] = dnx[j]; xvb[j] = xnx[j]; }
    }

    if (geo) {
        float p = Pr;
        #pragma unroll
        for (int n = 0; n < 16; n++) { P[n] = p; p *= Pr; }
    }
    #pragma unroll
    for (int n = 0; n < 16; n++) {
        size_t idx = ((((size_t)b * SEG_ + seg) << 4) + n) * ED_ + e;
        aprod[idx] = P[n];
        hend[idx]  = h[n];
    }
}

__global__ __launch_bounds__(256) void k_scan3(
        const bf16_t* __restrict__ dlt, const bf16_t* __restrict__ xs,
        const float* __restrict__ xd,    // B at +16, C at +32 (row stride 48)
        const bf16_t* __restrict__ xz,   // silu(z) at +ED
        const float* __restrict__ A_log, const float* __restrict__ Dp,
        const float* __restrict__ aprod, const float* __restrict__ hend,
        bf16_t* __restrict__ y, int layer) {
    __shared__ float s_BC[64][32];
    const int te = threadIdx.x;
    const int bi = blockIdx.x;
    const int seg = bi & (SEG_ - 1);
    const int eh  = (bi >> 4) & 1;
    const int b   = bi >> 5;
    const int e   = eh * 256 + te;
    const int rowbase = b * L_ + seg * SLEN_;

    {   // stage B|C rows: 64 x 32 floats
        int flat = te * 8;
        int r = flat >> 5, c = flat & 31;
        const float* src = xd + (size_t)(rowbase + r) * 48 + 16 + c;
        *(float4*)&s_BC[r][c]     = *(const float4*)(src);
        *(float4*)&s_BC[r][c + 4] = *(const float4*)(src + 4);
    }

    float A[16];
    bool geo = true;
    {
        const float* ap = A_log + ((size_t)layer * ED_ + e) * NS_;
        #pragma unroll
        for (int n = 0; n < 16; n++) A[n] = -__expf(ap[n]);
        #pragma unroll
        for (int n = 1; n < 16; n++)
            geo = geo && (fabsf(A[n] - (float)(n + 1) * A[0]) <= 1e-3f * (float)(n + 1) * fabsf(A[0]));
    }
    const float D = Dp[layer * ED_ + e];

    // cross-segment stitch (L2-hot)
    float h[16];
    #pragma unroll
    for (int n = 0; n < 16; n++) h[n] = 0.f;
    for (int s = 0; s < seg; s++) {
        const size_t pb = (((size_t)b * SEG_ + s) << 4) * ED_ + e;
        #pragma unroll
        for (int n = 0; n < 16; n++)
            h[n] = fmaf(aprod[pb + (size_t)n * ED_], h[n], hend[pb + (size_t)n * ED_]);
    }

    const bf16_t* dptr = dlt + (size_t)rowbase * ED_ + e;
    const bf16_t* xptr = xs  + (size_t)rowbase * ED_ + e;
    const bf16_t* zptr = xz  + (size_t)rowbase * (2 * ED_) + ED_ + e;
    bf16_t*       yptr = y   + (size_t)rowbase * ED_ + e;

    bf16_t dvb[8], xvb[8], zvb[8];
    #pragma unroll
    for (int j = 0; j < 8; j++) {
        dvb[j] = dptr[(size_t)j * ED_];
        xvb[j] = xptr[(size_t)j * ED_];
        zvb[j] = zptr[(size_t)j * (2 * ED_)];
    }
    __syncthreads();

    for (int sub = 0; sub < 8; sub++) {
        bf16_t dnx[8], xnx[8], znx[8];
        if (sub < 7) {
            const bf16_t* d2 = dptr + (size_t)(sub + 1) * 8 * ED_;
            const bf16_t* x2 = xptr + (size_t)(sub + 1) * 8 * ED_;
            const bf16_t* z2 = zptr + (size_t)(sub + 1) * 8 * (2 * ED_);
            #pragma unroll
            for (int j = 0; j < 8; j++) {
                dnx[j] = d2[(size_t)j * ED_];
                xnx[j] = x2[(size_t)j * ED_];
                znx[j] = z2[(size_t)j * (2 * ED_)];
            }
        }
        if (geo) {
            #pragma unroll
            for (int j = 0; j < 8; j++) {
                int l = sub * 8 + j;
                float dv = b2f(dvb[j]), xv = b2f(xvb[j]);
                float dx = dv * xv;
                float Bv[16], Cv[16];
                #pragma unroll
                for (int q = 0; q < 4; q++) {
                    *(float4*)&Bv[q * 4] = *(const float4*)&s_BC[l][q * 4];
                    *(float4*)&Cv[q * 4] = *(const float4*)&s_BC[l][16 + q * 4];
                }
                float r = __expf(dv * A[0]);
                float r2 = r * r, r4 = r2 * r2;
                float a0 = r, a1 = r2, a2 = r2 * r, a3 = r4;
                float y0 = D * xv, y1 = 0.f, y2 = 0.f, y3 = 0.f;
                #pragma unroll
                for (int q = 0; q < 4; q++) {
                    h[4*q+0] = fmaf(a0, h[4*q+0], dx * Bv[4*q+0]);
                    h[4*q+1] = fmaf(a1, h[4*q+1], dx * Bv[4*q+1]);
                    h[4*q+2] = fmaf(a2, h[4*q+2], dx * Bv[4*q+2]);
                    h[4*q+3] = fmaf(a3, h[4*q+3], dx * Bv[4*q+3]);
                    y0 = fmaf(Cv[4*q+0], h[4*q+0], y0);
                    y1 = fmaf(Cv[4*q+1], h[4*q+1], y1);
                    y2 = fmaf(Cv[4*q+2], h[4*q+2], y2);
                    y3 = fmaf(Cv[4*q+3], h[4*q+3], y3);
                    if (q < 3) { a0 *= r4; a1 *= r4; a2 *= r4; a3 *= r4; }
                }
                float yv = (y0 + y1) + (y2 + y3);
                yptr[(size_t)l * ED_] = __float2bfloat16(yv * b2f(zvb[j]));
            }
        } else {
            #pragma unroll
            for (int j = 0; j < 8; j++) {
                int l = sub * 8 + j;
                float dv = b2f(dvb[j]), xv = b2f(xvb[j]);
                float dx = dv * xv;
                float Bv[16], Cv[16];
                #pragma unroll
                for (int q = 0; q < 4; q++) {
                    *(float4*)&Bv[q * 4] = *(const float4*)&s_BC[l][q * 4];
                    *(float4*)&Cv[q * 4] = *(const float4*)&s_BC[l][16 + q * 4];
                }
                float y0 = D * xv, y1 = 0.f, y2 = 0.f, y3 = 0.f;
                #pragma unroll
                for (int n = 0; n < 16; n++) {
                    float a = __expf(dv * A[n]);
                    h[n] = fmaf(a, h[n], dx * Bv[n]);
                    float t = Cv[n] * h[n];
                    if ((n & 3) == 0) y0 += t;
                    else if ((n & 3) == 1) y1 += t;
                    else if ((n & 3) == 2) y2 += t;
                    else y3 += t;
                }
                float yv = (y0 + y1) + (y2 + y3);
                yptr[(size_t)l * ED_] = __float2bfloat16(yv * b2f(zvb[j]));
            }
        }
        #pragma unroll
        for (int j = 0; j < 8; j++) { dvb[j] = dnx[j]; xvb[j] = xnx[j]; zvb[j] = znx[j]; }
    }
}

// ---------------- final LN + head; wave-per-row, 4 rows/block
__global__ void k_final(const float* __restrict__ x,
                        const float* __restrict__ fg, const float* __restrict__ fb,
                        const float* __restrict__ hw, const float* __restrict__ hb,
                        float* __restrict__ out) {
    int lane = threadIdx.x & 63, w = threadIdx.x >> 6;
    int row = blockIdx.x * 4 + w;
    const float* xr = x + (size_t)row * DM_;
    float v[4];
    #pragma unroll
    for (int k = 0; k < 4; k++) v[k] = xr[lane + 64 * k];
    float s = (v[0] + v[1]) + (v[2] + v[3]);
    float q = (v[0] * v[0] + v[1] * v[1]) + (v[2] * v[2] + v[3] * v[3]);
    #pragma unroll
    for (int off = 32; off > 0; off >>= 1) {
        s += __shfl_xor(s, off, 64);
        q += __shfl_xor(q, off, 64);
    }
    float mean = s * (1.0f / DM_);
    float var = q * (1.0f / DM_) - mean * mean;
    float rstd = rsqrtf(var + 1e-5f);
    float s0 = 0.f, s1 = 0.f;
    #pragma unroll
    for (int k = 0; k < 4; k++) {
        int c = lane + 64 * k;
        float xf = (v[k] - mean) * rstd * fg[c] + fb[c];
        s0 += xf * hw[c * Q_ + 0];
        s1 += xf * hw[c * Q_ + 1];
    }
    #pragma unroll
    for (int off = 32; off > 0; off >>= 1) {
        s0 += __shfl_xor(s0, off, 64);
        s1 += __shfl_xor(s1, off, 64);
    }
    if (lane == 0) {
        out[row * Q_ + 0] = s0 + hb[0];
        out[row * Q_ + 1] = s1 + hb[1];
    }
}

extern "C" void kernel_launch(void* const* d_in, const int* in_sizes, int n_in,
                              void* d_out, int out_size, void* d_ws, size_t ws_size,
                              hipStream_t stream) {
    const int*   tokens    = (const int*)d_in[0];
    const float* T         = (const float*)d_in[1];
    const float* tok_embed = (const float*)d_in[2];
    const float* pos_embed = (const float*)d_in[3];
    const float* tw1       = (const float*)d_in[4];
    const float* tb1       = (const float*)d_in[5];
    const float* tw2       = (const float*)d_in[6];
    const float* tb2       = (const float*)d_in[7];
    const float* ag        = (const float*)d_in[8];
    const float* ab        = (const float*)d_in[9];
    const float* apw       = (const float*)d_in[10];
    const float* apb       = (const float*)d_in[11];
    const float* in_w      = (const float*)d_in[12];
    const float* conv_w    = (const float*)d_in[13];
    const float* conv_b    = (const float*)d_in[14];
    const float* xp_w      = (const float*)d_in[15];
    const float* dt_w      = (const float*)d_in[16];
    const float* dt_b      = (const float*)d_in[17];
    const float* A_log     = (const float*)d_in[18];
    const float* Dp        = (const float*)d_in[19];
    const float* out_w     = (const float*)d_in[20];
    const float* fg        = (const float*)d_in[21];
    const float* fb        = (const float*)d_in[22];
    const float* hw        = (const float*)d_in[23];
    const float* hb        = (const float*)d_in[24];
    float* out = (float*)d_out;

    const int ROWS = B_ * L_;   // 8192

    char* p = (char*)d_ws;
    float*  x      = (float*)p;   p += (size_t)ROWS * DM_ * 4;
    bf16_t* xz     = (bf16_t*)p;  p += (size_t)ROWS * 2 * ED_ * 2;
    bf16_t* xs     = (bf16_t*)p;  p += (size_t)ROWS * ED_ * 2;
    float*  xd     = (float*)p;   p += (size_t)ROWS * 48 * 4;
    bf16_t* dlt    = (bf16_t*)p;  p += (size_t)ROWS * ED_ * 2;
    bf16_t* y      = (bf16_t*)p;  p += (size_t)ROWS * ED_ * 2;
    float*  ss     = (float*)p;   p += (size_t)NL_ * B_ * 2 * DM_ * 4;
    float*  aprod  = (float*)p;   p += (size_t)B_ * SEG_ * NS_ * ED_ * 4;  // 4 MB
    float*  hendb  = (float*)p;   p += (size_t)B_ * SEG_ * NS_ * ED_ * 4;  // 4 MB
    bf16_t* in_wT  = (bf16_t*)p;  p += (size_t)NL_ * 2 * ED_ * DM_ * 2;
    bf16_t* xp_wT  = (bf16_t*)p;  p += (size_t)NL_ * 48 * ED_ * 2;
    bf16_t* out_wT = (bf16_t*)p;  p += (size_t)NL_ * DM_ * ED_ * 2;

    k_transpose_all<<<dim3(32, 16, 12), 256, 0, stream>>>(
        in_w, xp_w, out_w, in_wT, xp_wT, out_wT);
    k_prep<<<dim3(B_, NL_), 2 * DM_, 0, stream>>>(T, tw1, tb1, tw2, tb2, apw, apb, ss);
    k_embed<<<ROWS, DM_, 0, stream>>>(tokens, tok_embed, pos_embed, x);

    for (int i = 0; i < NL_; i++) {
        // xz = mod(LN(x)) @ in_w[i]  (LN fused; XCD-swizzled 1D grid, rows fast)
        k_ln_gemm_in<<<512, 256, 0, stream>>>(
            x, ag, ab, ss, in_wT + (size_t)i * 2 * ED_ * DM_, xz, i);
        // xs = silu(conv(xz))
        k_conv<<<(ROWS / 4) * (ED_ / 2) / 256, 256, 0, stream>>>(xz, conv_w, conv_b, xs, i);
        // xd[:,16:48] = xs @ xp_w[i]; dlt = softplus(rk @ dt_w + dt_b)
        k_gemm_xp_dlt<<<dim3(1, ROWS / 32), 256, 0, stream>>>(
            xs, xp_wT + (size_t)i * 48 * ED_, xd, dt_w, dt_b, dlt, i, ED_);
        // chunked scan
        k_scan1<<<B_ * 2 * SEG_, 256, 0, stream>>>(dlt, xs, xd, A_log, aprod, hendb, i);
        k_scan3<<<B_ * 2 * SEG_, 256, 0, stream>>>(
            dlt, xs, xd, xz, A_log, Dp, aprod, hendb, y, i);
        // x += y @ out_w[i]  (XCD-swizzled 1D grid, rows fast)
        k_mfma_gemm_acc<128, 64><<<256, 256, 0, stream>>>(
            y, out_wT + (size_t)i * DM_ * ED_, x, ROWS, DM_, ED_);
    }

    k_final<<<ROWS / 4, 256, 0, stream>>>(x, fg, fb, hw, hb, out);
}

// Round 16
// 571.296 us; speedup vs baseline: 1.0656x; 1.0200x over previous
//
#include <hip/hip_runtime.h>
#include <hip/hip_bf16.h>
#include <math.h>

#define B_   8
#define L_   1024
#define DM_  256
#define NL_  4
#define ED_  512
#define NS_  16
#define DC_  4
#define RK_  16
#define CD_  64
#define Q_   2

#define SEG_  16    // segments along L
#define SLEN_ 64    // L_/SEG_

typedef __hip_bfloat16 bf16_t;
typedef __attribute__((ext_vector_type(8))) short short8;
typedef __attribute__((ext_vector_type(4))) float floatx4;

__device__ __forceinline__ float geluf(float x) {
    return 0.5f * x * (1.0f + erff(x * 0.70710678118654752f));
}
__device__ __forceinline__ float siluf(float x) {
    return x / (1.0f + __expf(-x));
}
__device__ __forceinline__ float softplusf(float x) {
    return (x > 20.0f) ? x : log1pf(expf(x));
}
__device__ __forceinline__ float b2f(bf16_t v) { return __bfloat162float(v); }
__device__ __forceinline__ float bits2f(short u) {
    return __uint_as_float(((unsigned)(unsigned short)u) << 16);
}
__device__ __forceinline__ short f2bfbits(float v) {
    return __builtin_bit_cast(short, __float2bfloat16(v));
}

// ---------------- one-shot batched weight transpose + bf16 convert
__global__ void k_transpose_all(const float* __restrict__ in_w,
                                const float* __restrict__ xp_w,
                                const float* __restrict__ out_w,
                                bf16_t* __restrict__ in_wT,
                                bf16_t* __restrict__ xp_wT,
                                bf16_t* __restrict__ out_wT) {
    __shared__ float t[32][33];
    int z = blockIdx.z;
    int which = z >> 2, layer = z & 3;
    const float* src; bf16_t* dst; int R, C;
    if (which == 0)      { R = DM_; C = 2 * ED_; src = in_w;  dst = in_wT;  }
    else if (which == 1) { R = ED_; C = 48;      src = xp_w;  dst = xp_wT;  }
    else                 { R = ED_; C = DM_;     src = out_w; dst = out_wT; }
    src += (size_t)layer * R * C;
    dst += (size_t)layer * R * C;
    int c0 = blockIdx.x * 32, r0 = blockIdx.y * 32;
    if (c0 >= C || r0 >= R) return;
    int tx = threadIdx.x & 31, ty = threadIdx.x >> 5;   // 32 x 8
    #pragma unroll
    for (int i = 0; i < 32; i += 8) {
        int r = r0 + ty + i, c = c0 + tx;
        t[ty + i][tx] = (r < R && c < C) ? src[(size_t)r * C + c] : 0.f;
    }
    __syncthreads();
    #pragma unroll
    for (int i = 0; i < 32; i += 8) {
        int c = c0 + ty + i, r = r0 + tx;
        if (c < C && r < R) dst[(size_t)c * R + r] = __float2bfloat16(t[tx][ty + i]);
    }
}

// ---------------- embed
__global__ void k_embed(const int* __restrict__ tokens,
                        const float* __restrict__ tok_embed,
                        const float* __restrict__ pos_embed,
                        float* __restrict__ x) {
    int row = blockIdx.x;
    int d = threadIdx.x;
    int b = row / L_, l = row % L_;
    float v = pos_embed[l * DM_ + d];
    if (l > 0) {
        int tok = tokens[b * L_ + l - 1];
        v += tok_embed[tok * DM_ + d];
    }
    x[row * DM_ + d] = v;
}

// ---------------- conditioning + all-layer adaLN params in one launch
__global__ void k_prep(const float* __restrict__ T,
                       const float* __restrict__ tw1, const float* __restrict__ tb1,
                       const float* __restrict__ tw2, const float* __restrict__ tb2,
                       const float* __restrict__ apw, const float* __restrict__ apb,
                       float* __restrict__ ss) {
    __shared__ float h[CD_], cnd[CD_];
    int b = blockIdx.x, layer = blockIdx.y;
    int j = threadIdx.x;
    if (j < CD_) h[j] = geluf(T[b] * tw1[j] + tb1[j]);
    __syncthreads();
    if (j < CD_) {
        float acc = tb2[j];
        #pragma unroll
        for (int c = 0; c < CD_; c++) acc += h[c] * tw2[c * CD_ + j];
        cnd[j] = acc;
    }
    __syncthreads();
    const float* w = apw + (size_t)layer * CD_ * 2 * DM_;
    float acc = apb[layer * 2 * DM_ + j];
    #pragma unroll
    for (int c = 0; c < CD_; c++) acc += cnd[c] * w[c * 2 * DM_ + j];
    ss[((size_t)layer * B_ + b) * 2 * DM_ + j] = acc;
}

// ---------------- fused LN+adaLN + in-projection MFMA GEMM
// BM=64 for 4 blocks/CU occupancy. 1D grid, ROW-TILE FASTEST (128 row tiles
// == 0 mod 8 XCDs -> col blocks of a row tile share one XCD/L2).
__global__ __launch_bounds__(256) void k_ln_gemm_in(
        const float* __restrict__ x,
        const float* __restrict__ ag, const float* __restrict__ ab,
        const float* __restrict__ ss,
        const bf16_t* __restrict__ Bt,
        bf16_t* __restrict__ xz, int layer) {
    constexpr int BM = 64, BN = 128, K = 256, N = 2 * ED_;
    constexpr int TM = 2, TN = 4;
    __shared__ __align__(16) unsigned short sA[BM * 40];
    __shared__ __align__(16) unsigned short sB[BN * 40];
    __shared__ float s_mr[BM][2];
    __shared__ float s_prm[4 * DM_];   // g | b | (1+sc) | sh

    const int tid = threadIdx.x;
    const int wave = tid >> 6, lane = tid & 63;
    const int lrow = lane & 15, lq = lane >> 4;
    const int bi = blockIdx.x;
    const int row0 = (bi & 127) * BM, col0 = (bi >> 7) * BN;
    const int b = row0 / L_;
    const int wm0 = (wave >> 1) * 32, wn0 = (wave & 1) * 64;

    {
        s_prm[tid]       = ag[layer * DM_ + tid];
        s_prm[256 + tid] = ab[layer * DM_ + tid];
        const float* ssl = ss + ((size_t)layer * B_ + b) * 2 * DM_;
        s_prm[512 + tid] = 1.0f + ssl[tid];
        s_prm[768 + tid] = ssl[DM_ + tid];
    }
    {   // per-row mean/rstd: 4 threads per row (64 rows x 4)
        int r = tid >> 2, part = tid & 3;
        const float* xr = x + (size_t)(row0 + r) * K + part * 64;
        float s = 0.f, q = 0.f;
        #pragma unroll
        for (int i = 0; i < 16; i++) {
            float4 v = *(const float4*)(xr + i * 4);
            s += (v.x + v.y) + (v.z + v.w);
            q += (v.x * v.x + v.y * v.y) + (v.z * v.z + v.w * v.w);
        }
        s += __shfl_xor(s, 1, 64);  q += __shfl_xor(q, 1, 64);
        s += __shfl_xor(s, 2, 64);  q += __shfl_xor(q, 2, 64);
        if (part == 0) {
            float mean = s * (1.0f / K);
            float var = q * (1.0f / K) - mean * mean;
            s_mr[r][0] = mean;
            s_mr[r][1] = rsqrtf(var + 1e-5f);
        }
    }

    floatx4 acc[TM][TN];
    #pragma unroll
    for (int i = 0; i < TM; i++)
        #pragma unroll
        for (int j = 0; j < TN; j++) acc[i][j] = (floatx4)0.0f;

    float4 raf[2];      // 256 vectors for A (64 rows x 4), 1 per thread
    short8 rb[2];
    const int NKB = K / 32;   // 8
    {
        int m = tid >> 2, ko = (tid & 3) * 8;
        raf[0] = *(const float4*)(x + (size_t)(row0 + m) * K + ko);
        raf[1] = *(const float4*)(x + (size_t)(row0 + m) * K + ko + 4);
    }
    #pragma unroll
    for (int i = 0; i < 2; i++) {
        int v = tid + i * 256; int n = v >> 2, ko = (v & 3) * 8;
        rb[i] = *(const short8*)(Bt + (size_t)(col0 + n) * K + ko);
    }

    for (int kb = 0; kb < NKB; kb++) {
        __syncthreads();
        {
            int m = tid >> 2, ko = (tid & 3) * 8;
            int c0 = kb * 32 + ko;
            float mean = s_mr[m][0], rstd = s_mr[m][1];
            float av[8] = {raf[0].x, raf[0].y, raf[0].z, raf[0].w,
                           raf[1].x, raf[1].y, raf[1].z, raf[1].w};
            short8 o;
            #pragma unroll
            for (int j = 0; j < 8; j++) {
                int c = c0 + j;
                float ln = (av[j] - mean) * rstd * s_prm[c] + s_prm[256 + c];
                o[j] = f2bfbits(s_prm[512 + c] * ln + s_prm[768 + c]);
            }
            *(short8*)&sA[m * 40 + ko] = o;
        }
        #pragma unroll
        for (int i = 0; i < 2; i++) {
            int v = tid + i * 256; int n = v >> 2, ko = (v & 3) * 8;
            *(short8*)&sB[n * 40 + ko] = rb[i];
        }
        __syncthreads();
        if (kb + 1 < NKB) {
            int k0 = (kb + 1) * 32;
            {
                int m = tid >> 2, ko = (tid & 3) * 8;
                raf[0] = *(const float4*)(x + (size_t)(row0 + m) * K + k0 + ko);
                raf[1] = *(const float4*)(x + (size_t)(row0 + m) * K + k0 + ko + 4);
            }
            #pragma unroll
            for (int i = 0; i < 2; i++) {
                int v = tid + i * 256; int n = v >> 2, ko = (v & 3) * 8;
                rb[i] = *(const short8*)(Bt + (size_t)(col0 + n) * K + k0 + ko);
            }
        }
        short8 af[TM], bfr[TN];
        #pragma unroll
        for (int i = 0; i < TM; i++)
            af[i] = *(const short8*)&sA[(wm0 + i * 16 + lrow) * 40 + lq * 8];
        #pragma unroll
        for (int j = 0; j < TN; j++)
            bfr[j] = *(const short8*)&sB[(wn0 + j * 16 + lrow) * 40 + lq * 8];
        #pragma unroll
        for (int i = 0; i < TM; i++)
            #pragma unroll
            for (int j = 0; j < TN; j++)
                acc[i][j] = __builtin_amdgcn_mfma_f32_16x16x32_bf16(af[i], bfr[j], acc[i][j], 0, 0, 0);
    }

    #pragma unroll
    for (int i = 0; i < TM; i++) {
        int gr0 = row0 + wm0 + i * 16 + lq * 4;
        #pragma unroll
        for (int j = 0; j < TN; j++) {
            int gc = col0 + wn0 + j * 16 + lrow;
            #pragma unroll
            for (int r = 0; r < 4; r++) {
                float val = acc[i][j][r];
                if (gc >= ED_) val = siluf(val);
                xz[(size_t)(gr0 + r) * N + gc] = __float2bfloat16(val);
            }
        }
    }
}

// ---------------- MFMA bf16 GEMM (out-projection): C[M,N] += A[M,K] @ Bt[N,K]^T
// 1D grid, row-tile fastest (XCD swizzle): rt = bi % nrt, ct = bi / nrt.
template<int BM, int BN>
__global__ __launch_bounds__(256) void k_mfma_gemm_acc(
        const bf16_t* __restrict__ A, const bf16_t* __restrict__ Bt,
        float* __restrict__ Cf, int M, int N, int K) {
    constexpr int TM = BM / 32, TN = BN / 32;
    constexpr int VA = BM * 4, VB = BN * 4;
    constexpr int NA = (VA + 255) / 256;
    constexpr int NB = (VB + 255) / 256;
    __shared__ __align__(16) unsigned short sA[BM * 40];
    __shared__ __align__(16) unsigned short sB[BN * 40];

    const int tid = threadIdx.x;
    const int wave = tid >> 6, lane = tid & 63;
    const int lrow = lane & 15, lq = lane >> 4;
    const int nrt = M / BM;
    const int bi = blockIdx.x;
    const int row0 = (bi % nrt) * BM, col0 = (bi / nrt) * BN;
    const int wm0 = (wave >> 1) * (BM / 2);
    const int wn0 = (wave & 1) * (BN / 2);

    floatx4 acc[TM][TN];
    #pragma unroll
    for (int i = 0; i < TM; i++)
        #pragma unroll
        for (int j = 0; j < TN; j++) acc[i][j] = (floatx4)0.0f;

    short8 ra[NA], rb[NB];
    const int NKB = K / 32;

    #pragma unroll
    for (int i = 0; i < NA; i++) {
        int v = tid + i * 256;
        if (v < VA) {
            int m = v >> 2, ko = (v & 3) * 8;
            ra[i] = *(const short8*)(A + (size_t)(row0 + m) * K + ko);
        }
    }
    #pragma unroll
    for (int i = 0; i < NB; i++) {
        int v = tid + i * 256;
        if (v < VB) {
            int n = v >> 2, ko = (v & 3) * 8;
            rb[i] = *(const short8*)(Bt + (size_t)(col0 + n) * K + ko);
        }
    }

    for (int kb = 0; kb < NKB; kb++) {
        __syncthreads();
        #pragma unroll
        for (int i = 0; i < NA; i++) {
            int v = tid + i * 256;
            if (v < VA) {
                int m = v >> 2, ko = (v & 3) * 8;
                *(short8*)&sA[m * 40 + ko] = ra[i];
            }
        }
        #pragma unroll
        for (int i = 0; i < NB; i++) {
            int v = tid + i * 256;
            if (v < VB) {
                int n = v >> 2, ko = (v & 3) * 8;
                *(short8*)&sB[n * 40 + ko] = rb[i];
            }
        }
        __syncthreads();
        if (kb + 1 < NKB) {
            int k0 = (kb + 1) * 32;
            #pragma unroll
            for (int i = 0; i < NA; i++) {
                int v = tid + i * 256;
                if (v < VA) {
                    int m = v >> 2, ko = (v & 3) * 8;
                    ra[i] = *(const short8*)(A + (size_t)(row0 + m) * K + k0 + ko);
                }
            }
            #pragma unroll
            for (int i = 0; i < NB; i++) {
                int v = tid + i * 256;
                if (v < VB) {
                    int n = v >> 2, ko = (v & 3) * 8;
                    rb[i] = *(const short8*)(Bt + (size_t)(col0 + n) * K + k0 + ko);
                }
            }
        }
        short8 af[TM], bfr[TN];
        #pragma unroll
        for (int i = 0; i < TM; i++)
            af[i] = *(const short8*)&sA[(wm0 + i * 16 + lrow) * 40 + lq * 8];
        #pragma unroll
        for (int j = 0; j < TN; j++)
            bfr[j] = *(const short8*)&sB[(wn0 + j * 16 + lrow) * 40 + lq * 8];
        #pragma unroll
        for (int i = 0; i < TM; i++)
            #pragma unroll
            for (int j = 0; j < TN; j++)
                acc[i][j] = __builtin_amdgcn_mfma_f32_16x16x32_bf16(af[i], bfr[j], acc[i][j], 0, 0, 0);
    }

    #pragma unroll
    for (int i = 0; i < TM; i++) {
        int gr0 = row0 + wm0 + i * 16 + lq * 4;
        #pragma unroll
        for (int j = 0; j < TN; j++) {
            int gc = col0 + wn0 + j * 16 + lrow;
            #pragma unroll
            for (int r = 0; r < 4; r++)
                Cf[(size_t)(gr0 + r) * N + gc] += acc[i][j][r];
        }
    }
}

// ---------------- causal depthwise conv (DC=4) + SiLU: 4 rows x 2 e per thread
__global__ void k_conv(const bf16_t* __restrict__ xz,
                       const float* __restrict__ conv_w, const float* __restrict__ conv_b,
                       bf16_t* __restrict__ xs, int layer) {
    int t = blockIdx.x * blockDim.x + threadIdx.x;   // (ROWS/4) * (ED/2)
    int ep = t % (ED_ / 2);
    int rb4 = t / (ED_ / 2);
    int e = ep * 2;
    int row0 = rb4 * 4;
    int b = row0 / L_, l0 = row0 % L_;
    float4 w0 = *(const float4*)(conv_w + ((size_t)layer * ED_ + e) * DC_);
    float4 w1 = *(const float4*)(conv_w + ((size_t)layer * ED_ + e + 1) * DC_);
    float bias0 = conv_b[layer * ED_ + e];
    float bias1 = conv_b[layer * ED_ + e + 1];
    const float wa0[4] = {w0.x, w0.y, w0.z, w0.w};
    const float wa1[4] = {w1.x, w1.y, w1.z, w1.w};
    float v0[7], v1[7];
    #pragma unroll
    for (int k = 0; k < 7; k++) {
        int ll = l0 - 3 + k;
        if (ll >= 0) {
            __hip_bfloat162 v = *(const __hip_bfloat162*)(xz + ((size_t)(b * L_ + ll)) * (2 * ED_) + e);
            v0[k] = b2f(v.x); v1[k] = b2f(v.y);
        } else { v0[k] = 0.f; v1[k] = 0.f; }
    }
    #pragma unroll
    for (int j = 0; j < 4; j++) {
        float acc0 = bias0, acc1 = bias1;
        #pragma unroll
        for (int k = 0; k < DC_; k++) {
            acc0 = fmaf(v0[j + k], wa0[k], acc0);
            acc1 = fmaf(v1[j + k], wa1[k], acc1);
        }
        __hip_bfloat162 o;
        o.x = __float2bfloat16(siluf(acc0));
        o.y = __float2bfloat16(siluf(acc1));
        *(__hip_bfloat162*)(xs + (size_t)(row0 + j) * ED_ + e) = o;
    }
}

// ---------------- fused xp-projection + dlt: xd[:,16:48] = xs @ xp_w;
// dlt = softplus(rk @ dt_w + dt_b), rk = (xs @ xp_w)[:, :16]. grid (1, 256).
__global__ __launch_bounds__(256) void k_gemm_xp_dlt(
        const bf16_t* __restrict__ A, const bf16_t* __restrict__ Bt,
        float* __restrict__ xd,
        const float* __restrict__ dt_w, const float* __restrict__ dt_b,
        bf16_t* __restrict__ dlt, int layer, int K) {
    constexpr int BM = 32, BN = 64, N = 48;
    __shared__ __align__(16) unsigned short sA[BM * 40];
    __shared__ __align__(16) unsigned short sB[BN * 40];
    __shared__ float s_rk[32][17];

    const int tid = threadIdx.x;
    const int wave = tid >> 6, lane = tid & 63;
    const int lrow = lane & 15, lq = lane >> 4;
    const int row0 = blockIdx.y * BM;
    const int wm0 = (wave >> 1) * 16;
    const int wn0 = (wave & 1) * 32;

    floatx4 acc[2];
    acc[0] = (floatx4)0.0f; acc[1] = (floatx4)0.0f;

    short8 ra, rb;
    const int NKB = K / 32;   // 16
    {
        int v = tid;
        if (v < BM * 4) {
            int m = v >> 2, ko = (v & 3) * 8;
            ra = *(const short8*)(A + (size_t)(row0 + m) * K + ko);
        }
        int n = v >> 2, ko = (v & 3) * 8;
        rb = (n < N) ? *(const short8*)(Bt + (size_t)n * K + ko) : (short8)0;
    }
    for (int kb = 0; kb < NKB; kb++) {
        __syncthreads();
        if (tid < BM * 4) {
            int m = tid >> 2, ko = (tid & 3) * 8;
            *(short8*)&sA[m * 40 + ko] = ra;
        }
        { int n = tid >> 2, ko = (tid & 3) * 8; *(short8*)&sB[n * 40 + ko] = rb; }
        __syncthreads();
        if (kb + 1 < NKB) {
            int k0 = (kb + 1) * 32;
            if (tid < BM * 4) {
                int m = tid >> 2, ko = (tid & 3) * 8;
                ra = *(const short8*)(A + (size_t)(row0 + m) * K + k0 + ko);
            }
            int n = tid >> 2, ko = (tid & 3) * 8;
            rb = (n < N) ? *(const short8*)(Bt + (size_t)n * K + k0 + ko) : (short8)0;
        }
        short8 af = *(const short8*)&sA[(wm0 + lrow) * 40 + lq * 8];
        short8 b0 = *(const short8*)&sB[(wn0 + lrow) * 40 + lq * 8];
        short8 b1 = *(const short8*)&sB[(wn0 + 16 + lrow) * 40 + lq * 8];
        acc[0] = __builtin_amdgcn_mfma_f32_16x16x32_bf16(af, b0, acc[0], 0, 0, 0);
        acc[1] = __builtin_amdgcn_mfma_f32_16x16x32_bf16(af, b1, acc[1], 0, 0, 0);
    }

    #pragma unroll
    for (int j = 0; j < 2; j++) {
        int gc = wn0 + j * 16 + lrow;
        #pragma unroll
        for (int r = 0; r < 4; r++) {
            int gr = row0 + wm0 + lq * 4 + r;
            if (gc >= 16 && gc < 48) xd[(size_t)gr * 48 + gc] = acc[j][r];
        }
    }
    if ((wave & 1) == 0) {
        #pragma unroll
        for (int r = 0; r < 4; r++)
            s_rk[wm0 + lq * 4 + r][lrow] = acc[0][r];
    }
    __syncthreads();

    const int e = 2 * tid;
    float2 wv[16];
    #pragma unroll
    for (int r = 0; r < RK_; r++)
        wv[r] = *(const float2*)(dt_w + ((size_t)layer * RK_ + r) * ED_ + e);
    float2 bb = *(const float2*)(dt_b + (size_t)layer * ED_ + e);
    #pragma unroll 4
    for (int row = 0; row < 32; row++) {
        float a0 = bb.x, a1 = bb.y;
        #pragma unroll
        for (int r = 0; r < RK_; r++) {
            float rk = s_rk[row][r];
            a0 = fmaf(rk, wv[r].x, a0);
            a1 = fmaf(rk, wv[r].y, a1);
        }
        __hip_bfloat162 o;
        o.x = __float2bfloat16(softplusf(a0));
        o.y = __float2bfloat16(softplusf(a1));
        *(__hip_bfloat162*)(dlt + (size_t)(row0 + row) * ED_ + e) = o;
    }
}

// ======== chunked selective scan, thread = (b, e, seg), 16 n-states in registers ====
// Geometric-A fast path (runtime-verified): A_n = (n+1)*A_0 => a_n = r^{n+1}.

__global__ __launch_bounds__(256) void k_scan1(
        const bf16_t* __restrict__ dlt, const bf16_t* __restrict__ xs,
        const float* __restrict__ xd,    // B at +16 (row stride 48)
        const float* __restrict__ A_log,
        float* __restrict__ aprod, float* __restrict__ hend, int layer) {
    __shared__ float s_B[64][16];
    const int te = threadIdx.x;
    const int bi = blockIdx.x;
    const int seg = bi & (SEG_ - 1);
    const int eh  = (bi >> 4) & 1;
    const int b   = bi >> 5;
    const int e   = eh * 256 + te;
    const int rowbase = b * L_ + seg * SLEN_;

    {   // stage B rows: 64 x 16 floats
        int flat = te * 4;
        int r = flat >> 4, c = flat & 15;
        *(float4*)&s_B[r][c] = *(const float4*)(xd + (size_t)(rowbase + r) * 48 + 16 + c);
    }

    float A[16];
    bool geo = true;
    {
        const float* ap = A_log + ((size_t)layer * ED_ + e) * NS_;
        #pragma unroll
        for (int n = 0; n < 16; n++) A[n] = -__expf(ap[n]);
        #pragma unroll
        for (int n = 1; n < 16; n++)
            geo = geo && (fabsf(A[n] - (float)(n + 1) * A[0]) <= 1e-3f * (float)(n + 1) * fabsf(A[0]));
    }

    float h[16];
    #pragma unroll
    for (int n = 0; n < 16; n++) h[n] = 0.f;
    float Pr = 1.0f;
    float P[16];
    #pragma unroll
    for (int n = 0; n < 16; n++) P[n] = 1.f;

    const bf16_t* dptr = dlt + (size_t)rowbase * ED_ + e;
    const bf16_t* xptr = xs  + (size_t)rowbase * ED_ + e;

    bf16_t dvb[8], xvb[8];
    #pragma unroll
    for (int j = 0; j < 8; j++) {
        dvb[j] = dptr[(size_t)j * ED_];
        xvb[j] = xptr[(size_t)j * ED_];
    }
    __syncthreads();

    for (int sub = 0; sub < 8; sub++) {
        bf16_t dnx[8], xnx[8];
        if (sub < 7) {
            const bf16_t* d2 = dptr + (size_t)(sub + 1) * 8 * ED_;
            const bf16_t* x2 = xptr + (size_t)(sub + 1) * 8 * ED_;
            #pragma unroll
            for (int j = 0; j < 8; j++) {
                dnx[j] = d2[(size_t)j * ED_];
                xnx[j] = x2[(size_t)j * ED_];
            }
        }
        if (geo) {
            #pragma unroll
            for (int j = 0; j < 8; j++) {
                int l = sub * 8 + j;
                float dv = b2f(dvb[j]), xv = b2f(xvb[j]);
                float dx = dv * xv;
                float Bv[16];
                #pragma unroll
                for (int q = 0; q < 4; q++)
                    *(float4*)&Bv[q * 4] = *(const float4*)&s_B[l][q * 4];
                float r = __expf(dv * A[0]);
                float r2 = r * r, r4 = r2 * r2;
                float a0 = r, a1 = r2, a2 = r2 * r, a3 = r4;
                #pragma unroll
                for (int q = 0; q < 4; q++) {
                    h[4*q+0] = fmaf(a0, h[4*q+0], dx * Bv[4*q+0]);
                    h[4*q+1] = fmaf(a1, h[4*q+1], dx * Bv[4*q+1]);
                    h[4*q+2] = fmaf(a2, h[4*q+2], dx * Bv[4*q+2]);
                    h[4*q+3] = fmaf(a3, h[4*q+3], dx * Bv[4*q+3]);
                    if (q < 3) { a0 *= r4; a1 *= r4; a2 *= r4; a3 *= r4; }
                }
                Pr *= r;
            }
        } else {
            #pragma unroll
            for (int j = 0; j < 8; j++) {
                int l = sub * 8 + j;
                float dv = b2f(dvb[j]), xv = b2f(xvb[j]);
                float dx = dv * xv;
                float Bv[16];
                #pragma unroll
                for (int q = 0; q < 4; q++)
                    *(float4*)&Bv[q * 4] = *(const float4*)&s_B[l][q * 4];
                #pragma unroll
                for (int n = 0; n < 16; n++) {
                    float a = __expf(dv * A[n]);
                    h[n] = fmaf(a, h[n], dx * Bv[n]);
                    P[n] *= a;
                }
            }
        }
        #pragma unroll
        for (int j = 0; j < 8; j++) { dvb[j] = dnx[j]; xvb[j] = xnx[j]; }
    }

    if (geo) {
        float p = Pr;
        #pragma unroll
        for (int n = 0; n < 16; n++) { P[n] = p; p *= Pr; }
    }
    #pragma unroll
    for (int n = 0; n < 16; n++) {
        size_t idx = ((((size_t)b * SEG_ + seg) << 4) + n) * ED_ + e;
        aprod[idx] = P[n];
        hend[idx]  = h[n];
    }
}

__global__ __launch_bounds__(256) void k_scan3(
        const bf16_t* __restrict__ dlt, const bf16_t* __restrict__ xs,
        const float* __restrict__ xd,    // B at +16, C at +32 (row stride 48)
        const bf16_t* __restrict__ xz,   // silu(z) at +ED
        const float* __restrict__ A_log, const float* __restrict__ Dp,
        const float* __restrict__ aprod, const float* __restrict__ hend,
        bf16_t* __restrict__ y, int layer) {
    __shared__ float s_BC[64][32];
    const int te = threadIdx.x;
    const int bi = blockIdx.x;
    const int seg = bi & (SEG_ - 1);
    const int eh  = (bi >> 4) & 1;
    const int b   = bi >> 5;
    const int e   = eh * 256 + te;
    const int rowbase = b * L_ + seg * SLEN_;

    {   // stage B|C rows: 64 x 32 floats
        int flat = te * 8;
        int r = flat >> 5, c = flat & 31;
        const float* src = xd + (size_t)(rowbase + r) * 48 + 16 + c;
        *(float4*)&s_BC[r][c]     = *(const float4*)(src);
        *(float4*)&s_BC[r][c + 4] = *(const float4*)(src + 4);
    }

    float A[16];
    bool geo = true;
    {
        const float* ap = A_log + ((size_t)layer * ED_ + e) * NS_;
        #pragma unroll
        for (int n = 0; n < 16; n++) A[n] = -__expf(ap[n]);
        #pragma unroll
        for (int n = 1; n < 16; n++)
            geo = geo && (fabsf(A[n] - (float)(n + 1) * A[0]) <= 1e-3f * (float)(n + 1) * fabsf(A[0]));
    }
    const float D = Dp[layer * ED_ + e];

    // cross-segment stitch (L2-hot)
    float h[16];
    #pragma unroll
    for (int n = 0; n < 16; n++) h[n] = 0.f;
    for (int s = 0; s < seg; s++) {
        const size_t pb = (((size_t)b * SEG_ + s) << 4) * ED_ + e;
        #pragma unroll
        for (int n = 0; n < 16; n++)
            h[n] = fmaf(aprod[pb + (size_t)n * ED_], h[n], hend[pb + (size_t)n * ED_]);
    }

    const bf16_t* dptr = dlt + (size_t)rowbase * ED_ + e;
    const bf16_t* xptr = xs  + (size_t)rowbase * ED_ + e;
    const bf16_t* zptr = xz  + (size_t)rowbase * (2 * ED_) + ED_ + e;
    bf16_t*       yptr = y   + (size_t)rowbase * ED_ + e;

    bf16_t dvb[8], xvb[8], zvb[8];
    #pragma unroll
    for (int j = 0; j < 8; j++) {
        dvb[j] = dptr[(size_t)j * ED_];
        xvb[j] = xptr[(size_t)j * ED_];
        zvb[j] = zptr[(size_t)j * (2 * ED_)];
    }
    __syncthreads();

    for (int sub = 0; sub < 8; sub++) {
        bf16_t dnx[8], xnx[8], znx[8];
        if (sub < 7) {
            const bf16_t* d2 = dptr + (size_t)(sub + 1) * 8 * ED_;
            const bf16_t* x2 = xptr + (size_t)(sub + 1) * 8 * ED_;
            const bf16_t* z2 = zptr + (size_t)(sub + 1) * 8 * (2 * ED_);
            #pragma unroll
            for (int j = 0; j < 8; j++) {
                dnx[j] = d2[(size_t)j * ED_];
                xnx[j] = x2[(size_t)j * ED_];
                znx[j] = z2[(size_t)j * (2 * ED_)];
            }
        }
        if (geo) {
            #pragma unroll
            for (int j = 0; j < 8; j++) {
                int l = sub * 8 + j;
                float dv = b2f(dvb[j]), xv = b2f(xvb[j]);
                float dx = dv * xv;
                float Bv[16], Cv[16];
                #pragma unroll
                for (int q = 0; q < 4; q++) {
                    *(float4*)&Bv[q * 4] = *(const float4*)&s_BC[l][q * 4];
                    *(float4*)&Cv[q * 4] = *(const float4*)&s_BC[l][16 + q * 4];
                }
                float r = __expf(dv * A[0]);
                float r2 = r * r, r4 = r2 * r2;
                float a0 = r, a1 = r2, a2 = r2 * r, a3 = r4;
                float y0 = D * xv, y1 = 0.f, y2 = 0.f, y3 = 0.f;
                #pragma unroll
                for (int q = 0; q < 4; q++) {
                    h[4*q+0] = fmaf(a0, h[4*q+0], dx * Bv[4*q+0]);
                    h[4*q+1] = fmaf(a1, h[4*q+1], dx * Bv[4*q+1]);
                    h[4*q+2] = fmaf(a2, h[4*q+2], dx * Bv[4*q+2]);
                    h[4*q+3] = fmaf(a3, h[4*q+3], dx * Bv[4*q+3]);
                    y0 = fmaf(Cv[4*q+0], h[4*q+0], y0);
                    y1 = fmaf(Cv[4*q+1], h[4*q+1], y1);
                    y2 = fmaf(Cv[4*q+2], h[4*q+2], y2);
                    y3 = fmaf(Cv[4*q+3], h[4*q+3], y3);
                    if (q < 3) { a0 *= r4; a1 *= r4; a2 *= r4; a3 *= r4; }
                }
                float yv = (y0 + y1) + (y2 + y3);
                yptr[(size_t)l * ED_] = __float2bfloat16(yv * b2f(zvb[j]));
            }
        } else {
            #pragma unroll
            for (int j = 0; j < 8; j++) {
                int l = sub * 8 + j;
                float dv = b2f(dvb[j]), xv = b2f(xvb[j]);
                float dx = dv * xv;
                float Bv[16], Cv[16];
                #pragma unroll
                for (int q = 0; q < 4; q++) {
                    *(float4*)&Bv[q * 4] = *(const float4*)&s_BC[l][q * 4];
                    *(float4*)&Cv[q * 4] = *(const float4*)&s_BC[l][16 + q * 4];
                }
                float y0 = D * xv, y1 = 0.f, y2 = 0.f, y3 = 0.f;
                #pragma unroll
                for (int n = 0; n < 16; n++) {
                    float a = __expf(dv * A[n]);
                    h[n] = fmaf(a, h[n], dx * Bv[n]);
                    float t = Cv[n] * h[n];
                    if ((n & 3) == 0) y0 += t;
                    else if ((n & 3) == 1) y1 += t;
                    else if ((n & 3) == 2) y2 += t;
                    else y3 += t;
                }
                float yv = (y0 + y1) + (y2 + y3);
                yptr[(size_t)l * ED_] = __float2bfloat16(yv * b2f(zvb[j]));
            }
        }
        #pragma unroll
        for (int j = 0; j < 8; j++) { dvb[j] = dnx[j]; xvb[j] = xnx[j]; zvb[j] = znx[j]; }
    }
}

// ---------------- final LN + head; wave-per-row, 4 rows/block
__global__ void k_final(const float* __restrict__ x,
                        const float* __restrict__ fg, const float* __restrict__ fb,
                        const float* __restrict__ hw, const float* __restrict__ hb,
                        float* __restrict__ out) {
    int lane = threadIdx.x & 63, w = threadIdx.x >> 6;
    int row = blockIdx.x * 4 + w;
    const float* xr = x + (size_t)row * DM_;
    float v[4];
    #pragma unroll
    for (int k = 0; k < 4; k++) v[k] = xr[lane + 64 * k];
    float s = (v[0] + v[1]) + (v[2] + v[3]);
    float q = (v[0] * v[0] + v[1] * v[1]) + (v[2] * v[2] + v[3] * v[3]);
    #pragma unroll
    for (int off = 32; off > 0; off >>= 1) {
        s += __shfl_xor(s, off, 64);
        q += __shfl_xor(q, off, 64);
    }
    float mean = s * (1.0f / DM_);
    float var = q * (1.0f / DM_) - mean * mean;
    float rstd = rsqrtf(var + 1e-5f);
    float s0 = 0.f, s1 = 0.f;
    #pragma unroll
    for (int k = 0; k < 4; k++) {
        int c = lane + 64 * k;
        float xf = (v[k] - mean) * rstd * fg[c] + fb[c];
        s0 += xf * hw[c * Q_ + 0];
        s1 += xf * hw[c * Q_ + 1];
    }
    #pragma unroll
    for (int off = 32; off > 0; off >>= 1) {
        s0 += __shfl_xor(s0, off, 64);
        s1 += __shfl_xor(s1, off, 64);
    }
    if (lane == 0) {
        out[row * Q_ + 0] = s0 + hb[0];
        out[row * Q_ + 1] = s1 + hb[1];
    }
}

extern "C" void kernel_launch(void* const* d_in, const int* in_sizes, int n_in,
                              void* d_out, int out_size, void* d_ws, size_t ws_size,
                              hipStream_t stream) {
    const int*   tokens    = (const int*)d_in[0];
    const float* T         = (const float*)d_in[1];
    const float* tok_embed = (const float*)d_in[2];
    const float* pos_embed = (const float*)d_in[3];
    const float* tw1       = (const float*)d_in[4];
    const float* tb1       = (const float*)d_in[5];
    const float* tw2       = (const float*)d_in[6];
    const float* tb2       = (const float*)d_in[7];
    const float* ag        = (const float*)d_in[8];
    const float* ab        = (const float*)d_in[9];
    const float* apw       = (const float*)d_in[10];
    const float* apb       = (const float*)d_in[11];
    const float* in_w      = (const float*)d_in[12];
    const float* conv_w    = (const float*)d_in[13];
    const float* conv_b    = (const float*)d_in[14];
    const float* xp_w      = (const float*)d_in[15];
    const float* dt_w      = (const float*)d_in[16];
    const float* dt_b      = (const float*)d_in[17];
    const float* A_log     = (const float*)d_in[18];
    const float* Dp        = (const float*)d_in[19];
    const float* out_w     = (const float*)d_in[20];
    const float* fg        = (const float*)d_in[21];
    const float* fb        = (const float*)d_in[22];
    const float* hw        = (const float*)d_in[23];
    const float* hb        = (const float*)d_in[24];
    float* out = (float*)d_out;

    const int ROWS = B_ * L_;   // 8192

    char* p = (char*)d_ws;
    float*  x      = (float*)p;   p += (size_t)ROWS * DM_ * 4;
    bf16_t* xz     = (bf16_t*)p;  p += (size_t)ROWS * 2 * ED_ * 2;
    bf16_t* xs     = (bf16_t*)p;  p += (size_t)ROWS * ED_ * 2;
    float*  xd     = (float*)p;   p += (size_t)ROWS * 48 * 4;
    bf16_t* dlt    = (bf16_t*)p;  p += (size_t)ROWS * ED_ * 2;
    bf16_t* y      = (bf16_t*)p;  p += (size_t)ROWS * ED_ * 2;
    float*  ss     = (float*)p;   p += (size_t)NL_ * B_ * 2 * DM_ * 4;
    float*  aprod  = (float*)p;   p += (size_t)B_ * SEG_ * NS_ * ED_ * 4;  // 4 MB
    float*  hendb  = (float*)p;   p += (size_t)B_ * SEG_ * NS_ * ED_ * 4;  // 4 MB
    bf16_t* in_wT  = (bf16_t*)p;  p += (size_t)NL_ * 2 * ED_ * DM_ * 2;
    bf16_t* xp_wT  = (bf16_t*)p;  p += (size_t)NL_ * 48 * ED_ * 2;
    bf16_t* out_wT = (bf16_t*)p;  p += (size_t)NL_ * DM_ * ED_ * 2;

    k_transpose_all<<<dim3(32, 16, 12), 256, 0, stream>>>(
        in_w, xp_w, out_w, in_wT, xp_wT, out_wT);
    k_prep<<<dim3(B_, NL_), 2 * DM_, 0, stream>>>(T, tw1, tb1, tw2, tb2, apw, apb, ss);
    k_embed<<<ROWS, DM_, 0, stream>>>(tokens, tok_embed, pos_embed, x);

    for (int i = 0; i < NL_; i++) {
        // xz = mod(LN(x)) @ in_w[i]  (LN fused; BM=64, 1024 blocks, XCD swizzle)
        k_ln_gemm_in<<<1024, 256, 0, stream>>>(
            x, ag, ab, ss, in_wT + (size_t)i * 2 * ED_ * DM_, xz, i);
        // xs = silu(conv(xz))
        k_conv<<<(ROWS / 4) * (ED_ / 2) / 256, 256, 0, stream>>>(xz, conv_w, conv_b, xs, i);
        // xd[:,16:48] = xs @ xp_w[i]; dlt = softplus(rk @ dt_w + dt_b)
        k_gemm_xp_dlt<<<dim3(1, ROWS / 32), 256, 0, stream>>>(
            xs, xp_wT + (size_t)i * 48 * ED_, xd, dt_w, dt_b, dlt, i, ED_);
        // chunked scan
        k_scan1<<<B_ * 2 * SEG_, 256, 0, stream>>>(dlt, xs, xd, A_log, aprod, hendb, i);
        k_scan3<<<B_ * 2 * SEG_, 256, 0, stream>>>(
            dlt, xs, xd, xz, A_log, Dp, aprod, hendb, y, i);
        // x += y @ out_w[i]  (BM=64, 512 blocks, XCD swizzle)
        k_mfma_gemm_acc<64, 64><<<512, 256, 0, stream>>>(
            y, out_wT + (size_t)i * DM_ * ED_, x, ROWS, DM_, ED_);
    }

    k_final<<<ROWS / 4, 256, 0, stream>>>(x, fg, fb, hw, hb, out);
}